// Round 2
// baseline (376.247 us; speedup 1.0000x reference)
//
#include <hip/hip_runtime.h>
#include <hip/hip_bf16.h>
#include <cstdint>

// Sizes
#define Bz 4
#define Tz 256
#define Dz 256
#define D2z 512
#define Hz 4
#define DHz 128
#define BT (Bz*Tz)          // 1024 rows

__device__ __forceinline__ float dot4(float4 a, float4 b){
  return a.x*b.x + a.y*b.y + a.z*b.z + a.w*b.w;
}
__device__ __forceinline__ float sigmoidf_(float z){ return 1.f/(1.f+__expf(-z)); }

// ---------------- LayerNorm: one block per (b,t) row ----------------
__global__ void k_ln(const float* __restrict__ x, const float* __restrict__ g,
                     const float* __restrict__ bb, float* __restrict__ xn){
  int row = blockIdx.x;
  int tid = threadIdx.x;            // 256
  float v = x[(size_t)row*Dz + tid];
  float s = v, s2 = v*v;
  #pragma unroll
  for (int off=32; off; off>>=1){ s += __shfl_down(s, off); s2 += __shfl_down(s2, off); }
  __shared__ float ls[8];
  int wid = tid>>6, lane = tid&63;
  if (lane==0){ ls[wid]=s; ls[4+wid]=s2; }
  __syncthreads();
  if (tid==0){
    float a=ls[0]+ls[1]+ls[2]+ls[3], c=ls[4]+ls[5]+ls[6]+ls[7];
    float mu=a*(1.f/Dz), var=c*(1.f/Dz)-mu*mu;
    ls[0]=mu; ls[1]=rsqrtf(var+1e-5f);
  }
  __syncthreads();
  float mu=ls[0], rs=ls[1];
  xn[(size_t)row*Dz+tid] = (v-mu)*rs*g[tid]+bb[tid];
}

// ---------------- x_left / x_right GEMM: block per 8 rows, 512 thr ----------------
__global__ void k_lr(const float* __restrict__ xn, const float* __restrict__ WL,
                     const float* __restrict__ bL, const float* __restrict__ WR,
                     const float* __restrict__ bR, float* __restrict__ xl,
                     float* __restrict__ xr){
  __shared__ float xs[8][Dz];
  int r0 = blockIdx.x*8;
  int tid = threadIdx.x;            // 512
  ((float4*)&xs[0][0])[tid] = ((const float4*)(xn + (size_t)r0*Dz))[tid];
  __syncthreads();
  int o = tid;
  float accL[8]={0,0,0,0,0,0,0,0}, accR[8]={0,0,0,0,0,0,0,0};
  const float4* wl4 = (const float4*)(WL + (size_t)o*Dz);
  const float4* wr4 = (const float4*)(WR + (size_t)o*Dz);
  for (int k4=0;k4<Dz/4;k4++){
    float4 wl=wl4[k4], wr=wr4[k4];
    #pragma unroll
    for(int tt=0;tt<8;tt++){
      float4 xv = ((const float4*)xs[tt])[k4];
      accL[tt] += dot4(wl,xv);
      accR[tt] += dot4(wr,xv);
    }
  }
  float bl=bL[o], br=bR[o];
  #pragma unroll
  for(int tt=0;tt<8;tt++){
    xl[(size_t)(r0+tt)*D2z+o]=accL[tt]+bl;
    xr[(size_t)(r0+tt)*D2z+o]=accR[tt]+br;
  }
}

// ---------------- i_bar / f_bar: one wave per row ----------------
__global__ void __launch_bounds__(64) k_if(const float* __restrict__ xl,
    const float* __restrict__ Wi,const float* __restrict__ bi,
    const float* __restrict__ Wf,const float* __restrict__ bf,
    float* __restrict__ ib,float* __restrict__ fb){
  int row=blockIdx.x; int lane=threadIdx.x;
  const float4* xp=(const float4*)(xl+(size_t)row*D2z);
  float4 xa=xp[lane*2],xb=xp[lane*2+1];
  const float4* wi=(const float4*)Wi; const float4* wf=(const float4*)Wf;
  float si=dot4(wi[lane*2],xa)+dot4(wi[lane*2+1],xb);
  float sf=dot4(wf[lane*2],xa)+dot4(wf[lane*2+1],xb);
  #pragma unroll
  for(int off=1;off<64;off<<=1){si+=__shfl_xor(si,off);sf+=__shfl_xor(sf,off);}
  if(lane==0){ib[row]=si+bi[0];fb[row]=sf+bf[0];}
}

// ---------------- causal conv1d k=4: partial over 128-input-channel chunk ----------------
// grid (128 t-blocks, 4 chunks), 256 thr. Each thread: 2 output chans x 8 t's.
#define ICH 128
__global__ void __launch_bounds__(256) k_conv4(const float* __restrict__ xl,
                       const float* __restrict__ CW,
                       float* __restrict__ P0, float* __restrict__ P1,
                       float* __restrict__ P2, float* __restrict__ P3){
  __shared__ float xs[11][ICH];     // rows t0-3 .. t0+7, chunk's channels
  int tb = blockIdx.x;              // 0..127
  int chunk = blockIdx.y;           // 0..3
  int b = tb>>5; int t0 = (tb&31)*8;
  int ic0 = chunk*ICH;
  int tid = threadIdx.x;            // 256
  for (int idx=tid; idx<11*(ICH/4); idx+=256){   // 352 float4
    int j = idx>>5;                 // row 0..10 (32 float4 per row)
    int k4 = idx&31;
    int t = t0-3+j;
    float4 v = (t>=0) ? ((const float4*)(xl + (size_t)((b<<8)+t)*D2z + ic0))[k4]
                      : make_float4(0.f,0.f,0.f,0.f);
    ((float4*)xs[j])[k4]=v;
  }
  __syncthreads();
  int o0 = tid, o1 = tid+256;
  float acc0[8]={0,0,0,0,0,0,0,0}, acc1[8]={0,0,0,0,0,0,0,0};
  const float4* w40 = (const float4*)(CW + (size_t)o0*2048 + (size_t)ic0*4);
  const float4* w41 = (const float4*)(CW + (size_t)o1*2048 + (size_t)ic0*4);
  for (int i=0;i<ICH;i+=2){
    float4 wA0=w40[i], wB0=w40[i+1];
    float4 wA1=w41[i], wB1=w41[i+1];
    float2 xr2[11];
    #pragma unroll
    for(int j=0;j<11;j++) xr2[j]=*(const float2*)&xs[j][i];
    #pragma unroll
    for(int tt=0;tt<8;tt++){
      acc0[tt] += wA0.x*xr2[tt].x + wA0.y*xr2[tt+1].x + wA0.z*xr2[tt+2].x + wA0.w*xr2[tt+3].x
                + wB0.x*xr2[tt].y + wB0.y*xr2[tt+1].y + wB0.z*xr2[tt+2].y + wB0.w*xr2[tt+3].y;
      acc1[tt] += wA1.x*xr2[tt].x + wA1.y*xr2[tt+1].x + wA1.z*xr2[tt+2].x + wA1.w*xr2[tt+3].x
                + wB1.x*xr2[tt].y + wB1.y*xr2[tt+1].y + wB1.z*xr2[tt+2].y + wB1.w*xr2[tt+3].y;
    }
  }
  float* P = (chunk==0)?P0:(chunk==1)?P1:(chunk==2)?P2:P3;
  #pragma unroll
  for(int tt=0;tt<8;tt++){
    size_t row = (size_t)((b<<8)+t0+tt);
    P[row*D2z+o0]=acc0[tt];
    P[row*D2z+o1]=acc1[tt];
  }
}

// ---------------- combine partials + bias + swish -> xt ----------------
__global__ void __launch_bounds__(256) k_ccomb(const float* __restrict__ P0,
    const float* __restrict__ P1,const float* __restrict__ P2,
    const float* __restrict__ P3,const float* __restrict__ cb,
    float* __restrict__ xt){
  int idx = blockIdx.x*256 + threadIdx.x;       // 0..131071 float4s
  float4 a=((const float4*)P0)[idx], b=((const float4*)P1)[idx];
  float4 c=((const float4*)P2)[idx], d=((const float4*)P3)[idx];
  float4 cbv=((const float4*)cb)[idx&127];
  float4 r;
  float y;
  y=a.x+b.x+c.x+d.x+cbv.x; r.x=y*sigmoidf_(y);
  y=a.y+b.y+c.y+d.y+cbv.y; r.y=y*sigmoidf_(y);
  y=a.z+b.z+c.z+d.z+cbv.z; r.z=y*sigmoidf_(y);
  y=a.w+b.w+c.w+d.w+cbv.w; r.w=y*sigmoidf_(y);
  ((float4*)xt)[idx]=r;
}

// ---------------- o-gate (Wo, sigmoid) + v (block-diag Wv): 4 rows, 2 o/thread ----------------
__global__ void k_wov(const float* __restrict__ xl,const float* __restrict__ Wo,
                      const float* __restrict__ bo,const float* __restrict__ Wv,
                      float* __restrict__ og,float* __restrict__ vv){
  __shared__ float xs[4][D2z];
  int r0=blockIdx.x*4; int tid=threadIdx.x;   // 256
  for(int idx=tid;idx<512;idx+=256)
    ((float4*)&xs[0][0])[idx]=((const float4*)(xl+(size_t)r0*D2z))[idx];
  __syncthreads();
  int o0=tid,o1=tid+256;
  float a0[4]={0,0,0,0},a1[4]={0,0,0,0};
  const float4* w0=(const float4*)(Wo+(size_t)o0*D2z);
  const float4* w1=(const float4*)(Wo+(size_t)o1*D2z);
  for(int i4=0;i4<128;i4++){
    float4 wa=w0[i4],wb=w1[i4];
    #pragma unroll
    for(int tt=0;tt<4;tt++){
      float4 xv=((const float4*)xs[tt])[i4];
      a0[tt]+=dot4(wa,xv); a1[tt]+=dot4(wb,xv);
    }
  }
  float v0[4]={0,0,0,0},v1[4]={0,0,0,0};
  int h0=o0>>7,h1=o1>>7;
  const float4* wv0=(const float4*)Wv+(size_t)o0*32;
  const float4* wv1=(const float4*)Wv+(size_t)o1*32;
  for(int i4=0;i4<32;i4++){
    float4 wa=wv0[i4],wb=wv1[i4];
    #pragma unroll
    for(int tt=0;tt<4;tt++){
      float4 xva=((const float4*)xs[tt])[h0*32+i4];
      float4 xvb=((const float4*)xs[tt])[h1*32+i4];
      v0[tt]+=dot4(wa,xva); v1[tt]+=dot4(wb,xvb);
    }
  }
  float bo0=bo[o0],bo1=bo[o1];
  #pragma unroll
  for(int tt=0;tt<4;tt++){
    size_t row=r0+tt;
    og[row*D2z+o0]=sigmoidf_(a0[tt]+bo0);
    og[row*D2z+o1]=sigmoidf_(a1[tt]+bo1);
    vv[row*D2z+o0]=v0[tt];
    vv[row*D2z+o1]=v1[tt];
  }
}

// ---------------- q,k (block-diag) + skip GEMM from x_trans ----------------
__global__ void k_qks(const float* __restrict__ xt,const float* __restrict__ Wq,
                      const float* __restrict__ Wk,const float* __restrict__ SW,
                      float* __restrict__ qq,float* __restrict__ kk,
                      float* __restrict__ sk){
  __shared__ float xs[4][D2z];
  int r0=blockIdx.x*4; int tid=threadIdx.x;   // 256
  for(int idx=tid;idx<512;idx+=256)
    ((float4*)&xs[0][0])[idx]=((const float4*)(xt+(size_t)r0*D2z))[idx];
  __syncthreads();
  int o0=tid,o1=tid+256;
  float s0[4]={0,0,0,0},s1[4]={0,0,0,0};
  const float4* w0=(const float4*)(SW+(size_t)o0*D2z);
  const float4* w1=(const float4*)(SW+(size_t)o1*D2z);
  for(int i4=0;i4<128;i4++){
    float4 wa=w0[i4],wb=w1[i4];
    #pragma unroll
    for(int tt=0;tt<4;tt++){
      float4 xv=((const float4*)xs[tt])[i4];
      s0[tt]+=dot4(wa,xv); s1[tt]+=dot4(wb,xv);
    }
  }
  float q0[4]={0,0,0,0},q1[4]={0,0,0,0},k0[4]={0,0,0,0},k1[4]={0,0,0,0};
  int h0=o0>>7,h1=o1>>7;
  const float4* wq0=(const float4*)Wq+(size_t)o0*32; const float4* wq1=(const float4*)Wq+(size_t)o1*32;
  const float4* wk0=(const float4*)Wk+(size_t)o0*32; const float4* wk1=(const float4*)Wk+(size_t)o1*32;
  for(int i4=0;i4<32;i4++){
    float4 qa=wq0[i4],qb=wq1[i4],ka=wk0[i4],kb2=wk1[i4];
    #pragma unroll
    for(int tt=0;tt<4;tt++){
      float4 xva=((const float4*)xs[tt])[h0*32+i4];
      float4 xvb=((const float4*)xs[tt])[h1*32+i4];
      q0[tt]+=dot4(qa,xva); q1[tt]+=dot4(qb,xvb);
      k0[tt]+=dot4(ka,xva); k1[tt]+=dot4(kb2,xvb);
    }
  }
  #pragma unroll
  for(int tt=0;tt<4;tt++){
    size_t row=r0+tt;
    qq[row*D2z+o0]=q0[tt];        qq[row*D2z+o1]=q1[tt];
    kk[row*D2z+o0]=0.0625f*k0[tt]; kk[row*D2z+o1]=0.0625f*k1[tt];  // SCALE = D^-0.5
    sk[row*D2z+o0]=s0[tt];        sk[row*D2z+o1]=s1[tt];
  }
}

// ---------------- decay precompute: F = cumsum(fb), G = ib - F, Mx = max(0, cummax(G)) ----------------
__global__ void __launch_bounds__(256) k_decay(
    const float* __restrict__ ibar, const float* __restrict__ fbar,
    float* __restrict__ G, float* __restrict__ Mx){
  int b = blockIdx.x, t = threadIdx.x;   // 256 threads = Tz
  __shared__ float buf[Tz];
  float f = fbar[b*Tz + t];
  buf[t] = f; __syncthreads();
  float v = f;
  for (int off=1; off<Tz; off<<=1){
    float add = (t >= off) ? buf[t-off] : 0.f;
    __syncthreads();
    v += add; buf[t] = v;
    __syncthreads();
  }
  float F = v;
  float g = ibar[b*Tz+t] - F;
  G[b*Tz+t] = g;
  buf[t] = g; __syncthreads();
  v = g;
  for (int off=1; off<Tz; off<<=1){
    float other = (t >= off) ? buf[t-off] : -3.4e38f;
    __syncthreads();
    v = fmaxf(v, other); buf[t] = v;
    __syncthreads();
  }
  Mx[b*Tz+t] = fmaxf(v, 0.f);
}

// ---------------- scan as causal decayed attention ----------------
#define TTa 8
__global__ void __launch_bounds__(256) k_attn(
    const float* __restrict__ qq, const float* __restrict__ kk,
    const float* __restrict__ vv, const float* __restrict__ og,
    const float* __restrict__ G, const float* __restrict__ Mx,
    float* __restrict__ hs){
  int b  = blockIdx.y;
  int t0 = blockIdx.x * TTa;
  int tid = threadIdx.x;            // 256
  __shared__ float Qs[TTa][D2z];    // 16 KB
  __shared__ float Ps[TTa][Tz];     // 8 KB
  __shared__ float Gs[Tz];          // 1 KB
  __shared__ float inv_d[TTa];
  __shared__ float mxs[TTa];

  const float* qb = qq + ((size_t)b*Tz + t0)*D2z;
  for (int idx=tid; idx<TTa*D2z/4; idx+=256)
    ((float4*)&Qs[0][0])[idx] = ((const float4*)qb)[idx];
  Gs[tid] = G[b*Tz + tid];
  if (tid < TTa) mxs[tid] = Mx[b*Tz + t0 + tid];
  __syncthreads();

  int s = tid;
  int smax = t0 + TTa - 1;
  {
    float acc[TTa] = {0,0,0,0,0,0,0,0};
    if (s <= smax){
      const float4* kp = (const float4*)(kk + ((size_t)b*Tz + s)*D2z);
      for (int k4=0; k4<D2z/4; k4++){
        float4 kv = kp[k4];
        #pragma unroll
        for (int tt=0; tt<TTa; tt++){
          float4 qv = ((const float4*)Qs[tt])[k4];
          acc[tt] += dot4(kv,qv);
        }
      }
    }
    float g = Gs[s];
    #pragma unroll
    for (int tt=0; tt<TTa; tt++){
      int t = t0 + tt;
      Ps[tt][s] = (s <= t) ? acc[tt] * __expf(g - mxs[tt]) : 0.f;
    }
  }
  __syncthreads();
  {
    int wv = tid >> 6, lane = tid & 63;
    #pragma unroll
    for (int r=0; r<2; r++){
      int tt = wv*2 + r;
      float ssum = Ps[tt][lane] + Ps[tt][lane+64] + Ps[tt][lane+128] + Ps[tt][lane+192];
      #pragma unroll
      for (int off=1; off<64; off<<=1) ssum += __shfl_xor(ssum, off);
      if (lane==0) inv_d[tt] = 1.f / (fmaxf(fabsf(ssum), 1.f) + 1e-8f);
    }
  }
  __syncthreads();
  {
    int c0 = tid, c1 = tid + 256;
    float a0[TTa]={0,0,0,0,0,0,0,0}, a1[TTa]={0,0,0,0,0,0,0,0};
    const float* vb = vv + (size_t)b*Tz*D2z;
    for (int s2=0; s2<=smax; s2+=4){
      float4 pr[TTa];
      #pragma unroll
      for (int tt=0; tt<TTa; tt++) pr[tt] = *(const float4*)&Ps[tt][s2];
      #pragma unroll
      for (int j=0; j<4; j++){
        int sj = s2 + j;
        float v0 = vb[(size_t)sj*D2z + c0];
        float v1 = vb[(size_t)sj*D2z + c1];
        #pragma unroll
        for (int tt=0; tt<TTa; tt++){
          float p = ((const float*)&pr[tt])[j];
          a0[tt] += p*v0; a1[tt] += p*v1;
        }
      }
    }
    #pragma unroll
    for (int tt=0; tt<TTa; tt++){
      size_t row = (size_t)b*Tz + t0 + tt;
      float id = inv_d[tt];
      hs[row*D2z + c0] = og[row*D2z + c0] * a0[tt] * id;
      hs[row*D2z + c1] = og[row*D2z + c1] * a1[tt] * id;
    }
  }
}

// ---------------- GroupNorm stats per (b,h): mean & rstd over (T,DH) ----------------
__global__ void k_gnstat(const float* __restrict__ hs,float* __restrict__ gmu,
                         float* __restrict__ grs){
  int g=blockIdx.x; int b=g>>2,h=g&3; int tid=threadIdx.x;  // 256 thr
  float s=0.f,s2=0.f;
  const float* base=hs+(size_t)b*Tz*D2z+h*DHz;
  for(int idx=tid;idx<Tz*DHz;idx+=256){
    int t=idx>>7,c=idx&127;
    float v=base[(size_t)t*D2z+c];
    s+=v;s2+=v*v;
  }
  #pragma unroll
  for(int off=32;off;off>>=1){s+=__shfl_down(s,off);s2+=__shfl_down(s2,off);}
  __shared__ float ls[8];
  int wid=tid>>6,lane=tid&63;
  if(lane==0){ls[wid]=s;ls[4+wid]=s2;}
  __syncthreads();
  if(tid==0){
    float S=ls[0]+ls[1]+ls[2]+ls[3],S2=ls[4]+ls[5]+ls[6]+ls[7];
    float mu=S*(1.f/(Tz*DHz));
    float var=S2*(1.f/(Tz*DHz))-mu*mu;
    gmu[g]=mu; grs[g]=rsqrtf(fmaxf(var,0.f)+1e-5f);
  }
}

// ---------------- finish: GN apply + skip + *swish(x_right) + W_last GEMM + residual ----------------
__global__ void k_final(const float* __restrict__ hs,const float* __restrict__ gmu,
    const float* __restrict__ grs,const float* __restrict__ gng,
    const float* __restrict__ gnb,const float* __restrict__ sk,
    const float* __restrict__ xr,const float* __restrict__ WL,
    const float* __restrict__ bl,const float* __restrict__ x,
    float* __restrict__ out){
  __shared__ float hm[4][D2z];
  int r0=blockIdx.x*4; int b=r0>>8; int tid=threadIdx.x;   // 256 thr
  for(int idx=tid;idx<4*D2z;idx+=256){
    int tt=idx>>9,c=idx&511;
    size_t row=r0+tt;
    int g=(b<<2)+(c>>7);
    float v=hs[row*D2z+c];
    float hg=(v-gmu[g])*grs[g]*gng[c]+gnb[c]+sk[row*D2z+c];
    float xv=xr[row*D2z+c];
    hm[tt][c]=hg*(xv*sigmoidf_(xv));
  }
  __syncthreads();
  int d=tid;
  float acc[4]={0,0,0,0};
  const float4* w4=(const float4*)(WL+(size_t)d*D2z);
  for(int i4=0;i4<128;i4++){
    float4 w=w4[i4];
    #pragma unroll
    for(int tt=0;tt<4;tt++){
      float4 hv=((const float4*)hm[tt])[i4];
      acc[tt]+=dot4(w,hv);
    }
  }
  float bd=bl[d];
  #pragma unroll
  for(int tt=0;tt<4;tt++){
    size_t row=r0+tt;
    out[row*Dz+d]=acc[tt]+bd+x[row*Dz+d];
  }
}

extern "C" void kernel_launch(void* const* d_in, const int* in_sizes, int n_in,
                              void* d_out, int out_size, void* d_ws, size_t ws_size,
                              hipStream_t stream) {
  (void)in_sizes; (void)n_in; (void)out_size; (void)ws_size;
  const float* x      = (const float*)d_in[0];
  const float* ln_g   = (const float*)d_in[1];
  const float* ln_b   = (const float*)d_in[2];
  const float* W_left = (const float*)d_in[3];
  const float* b_left = (const float*)d_in[4];
  const float* W_right= (const float*)d_in[5];
  const float* b_right= (const float*)d_in[6];
  const float* Wi     = (const float*)d_in[7];
  const float* bi     = (const float*)d_in[8];
  const float* Wf     = (const float*)d_in[9];
  const float* bf     = (const float*)d_in[10];
  const float* Wo     = (const float*)d_in[11];
  const float* bo     = (const float*)d_in[12];
  const float* Wq     = (const float*)d_in[13];
  const float* Wk     = (const float*)d_in[14];
  const float* Wv     = (const float*)d_in[15];
  const float* conv_w = (const float*)d_in[16];
  const float* conv_b = (const float*)d_in[17];
  const float* skip_W = (const float*)d_in[18];
  const float* gn_g   = (const float*)d_in[19];
  const float* gn_b   = (const float*)d_in[20];
  const float* W_last = (const float*)d_in[21];
  const float* b_last = (const float*)d_in[22];
  float* out = (float*)d_out;

  float* ws = (float*)d_ws;
  float* xn   = ws;                  // 262144
  float* xl   = ws + 262144;         // 524288
  float* xr   = ws + 786432;         // 524288
  float* xt   = ws + 1310720;        // 524288
  float* og   = ws + 1835008;        // 524288
  float* vv   = ws + 2359296;        // 524288
  float* qq   = ws + 2883584;        // 524288
  float* kk   = ws + 3407872;        // 524288
  float* sk   = ws + 3932160;        // 524288
  float* hs   = ws + 4456448;        // 524288
  float* ibar = ws + 4980736;        // 1024
  float* fbar = ws + 4981760;        // 1024
  float* gmu  = ws + 4982784;        // 16
  float* grs  = ws + 4982800;        // 16
  float* Gd   = ws + 4982816;        // 1024
  float* Mxd  = ws + 4983840;        // 1024

  k_ln    <<<BT, 256, 0, stream>>>(x, ln_g, ln_b, xn);
  k_lr    <<<BT/8, 512, 0, stream>>>(xn, W_left, b_left, W_right, b_right, xl, xr);
  k_if    <<<BT, 64, 0, stream>>>(xl, Wi, bi, Wf, bf, ibar, fbar);
  k_decay <<<Bz, 256, 0, stream>>>(ibar, fbar, Gd, Mxd);
  // conv partials land in qq,kk,sk,hs (free until k_qks/k_attn), combined into xt
  k_conv4 <<<dim3(BT/8, 4), 256, 0, stream>>>(xl, conv_w, qq, kk, sk, hs);
  k_ccomb <<<BT*D2z/4/256, 256, 0, stream>>>(qq, kk, sk, hs, conv_b, xt);
  k_wov   <<<BT/4, 256, 0, stream>>>(xl, Wo, bo, Wv, og, vv);
  k_qks   <<<BT/4, 256, 0, stream>>>(xt, Wq, Wk, skip_W, qq, kk, sk);
  k_attn  <<<dim3(Tz/TTa, Bz), 256, 0, stream>>>(qq, kk, vv, og, Gd, Mxd, hs);
  k_gnstat<<<Bz*Hz, 256, 0, stream>>>(hs, gmu, grs);
  k_final <<<BT/4, 256, 0, stream>>>(hs, gmu, grs, gn_g, gn_b, sk, xr, W_last, b_last, x, out);
}

// Round 3
// 330.038 us; speedup vs baseline: 1.1400x; 1.1400x over previous
//
#include <hip/hip_runtime.h>
#include <hip/hip_bf16.h>
#include <cstdint>

// Sizes
#define Bz 4
#define Tz 256
#define Dz 256
#define D2z 512
#define Hz 4
#define DHz 128
#define BT (Bz*Tz)          // 1024 rows

__device__ __forceinline__ float dot4(float4 a, float4 b){
  return a.x*b.x + a.y*b.y + a.z*b.z + a.w*b.w;
}
__device__ __forceinline__ float sigmoidf_(float z){ return 1.f/(1.f+__expf(-z)); }

// ---------------- fused LayerNorm + x_left/x_right GEMM: 8 rows, 512 thr ----------------
__global__ void __launch_bounds__(512) k_lnlr(
    const float* __restrict__ x, const float* __restrict__ lg,
    const float* __restrict__ lb, const float* __restrict__ WL,
    const float* __restrict__ bL, const float* __restrict__ WR,
    const float* __restrict__ bR, float* __restrict__ xl,
    float* __restrict__ xr){
  __shared__ float xs[8][Dz];
  int r0 = blockIdx.x*8;
  int tid = threadIdx.x;            // 512
  ((float4*)&xs[0][0])[tid] = ((const float4*)(x + (size_t)r0*Dz))[tid];
  __syncthreads();
  // wave w normalizes row w (256 elems, 4/lane)
  int w = tid>>6, lane = tid&63;
  float a0 = xs[w][lane],     a1 = xs[w][lane+64];
  float a2 = xs[w][lane+128], a3 = xs[w][lane+192];
  float s  = a0+a1+a2+a3;
  float s2 = a0*a0+a1*a1+a2*a2+a3*a3;
  #pragma unroll
  for (int off=1; off<64; off<<=1){ s += __shfl_xor(s, off); s2 += __shfl_xor(s2, off); }
  float mu = s*(1.f/Dz);
  float rs = rsqrtf(s2*(1.f/Dz)-mu*mu+1e-5f);
  xs[w][lane]     = (a0-mu)*rs*lg[lane]    +lb[lane];
  xs[w][lane+64]  = (a1-mu)*rs*lg[lane+64] +lb[lane+64];
  xs[w][lane+128] = (a2-mu)*rs*lg[lane+128]+lb[lane+128];
  xs[w][lane+192] = (a3-mu)*rs*lg[lane+192]+lb[lane+192];
  __syncthreads();
  int o = tid;
  float accL[8]={0,0,0,0,0,0,0,0}, accR[8]={0,0,0,0,0,0,0,0};
  const float4* wl4 = (const float4*)(WL + (size_t)o*Dz);
  const float4* wr4 = (const float4*)(WR + (size_t)o*Dz);
  #pragma unroll 2
  for (int k4=0;k4<Dz/4;k4++){
    float4 wl=wl4[k4], wr=wr4[k4];
    #pragma unroll
    for(int tt=0;tt<8;tt++){
      float4 xv = ((const float4*)xs[tt])[k4];
      accL[tt] += dot4(wl,xv);
      accR[tt] += dot4(wr,xv);
    }
  }
  float bl=bL[o], br=bR[o];
  #pragma unroll
  for(int tt=0;tt<8;tt++){
    xl[(size_t)(r0+tt)*D2z+o]=accL[tt]+bl;
    xr[(size_t)(r0+tt)*D2z+o]=accR[tt]+br;
  }
}

// ---------------- i_bar / f_bar: one wave per row ----------------
__global__ void __launch_bounds__(64) k_if(const float* __restrict__ xl,
    const float* __restrict__ Wi,const float* __restrict__ bi,
    const float* __restrict__ Wf,const float* __restrict__ bf,
    float* __restrict__ ib,float* __restrict__ fb){
  int row=blockIdx.x; int lane=threadIdx.x;
  const float4* xp=(const float4*)(xl+(size_t)row*D2z);
  float4 xa=xp[lane*2],xb=xp[lane*2+1];
  const float4* wi=(const float4*)Wi; const float4* wf=(const float4*)Wf;
  float si=dot4(wi[lane*2],xa)+dot4(wi[lane*2+1],xb);
  float sf=dot4(wf[lane*2],xa)+dot4(wf[lane*2+1],xb);
  #pragma unroll
  for(int off=1;off<64;off<<=1){si+=__shfl_xor(si,off);sf+=__shfl_xor(sf,off);}
  if(lane==0){ib[row]=si+bi[0];fb[row]=sf+bf[0];}
}

// ---------------- causal conv1d k=4 + swish: block=(8 t's, 256 o's) ----------------
// 4-channel batched inner loop: 4 b128 weight loads + 11 broadcast b128 LDS
// reads per 128 FMA; unroll 2 keeps 8 weight loads in flight over L2.
__global__ void __launch_bounds__(256) k_conv(const float* __restrict__ xl,
                       const float* __restrict__ CW,
                       const float* __restrict__ cb, float* __restrict__ xt){
  __shared__ float xs[11][D2z];     // rows t0-3 .. t0+7
  int bt8 = blockIdx.x;             // 0..127
  int oh  = blockIdx.y;             // 0..1
  int b = bt8>>5; int t0 = (bt8&31)*8;
  int tid = threadIdx.x;            // 256
  for(int idx=tid; idx<11*(D2z/4); idx+=256){
    int j = idx>>7;                 // row 0..10 (128 float4 per row)
    int k4 = idx&127;
    int t = t0-3+j;
    float4 v = (t>=0) ? ((const float4*)(xl + (size_t)((b<<8)+t)*D2z))[k4]
                      : make_float4(0.f,0.f,0.f,0.f);
    ((float4*)xs[j])[k4]=v;
  }
  __syncthreads();
  int o = oh*256 + tid;
  float acc[8]={0,0,0,0,0,0,0,0};
  const float4* w4=(const float4*)(CW+(size_t)o*2048);  // [i] -> taps 0..3 of chan i
  #pragma unroll 2
  for(int i=0;i<D2z;i+=4){
    float4 w0=w4[i], w1=w4[i+1], w2=w4[i+2], w3=w4[i+3];
    float4 xr4[11];
    #pragma unroll
    for(int j=0;j<11;j++) xr4[j]=*(const float4*)&xs[j][i];
    #pragma unroll
    for(int tt=0;tt<8;tt++){
      acc[tt] += w0.x*xr4[tt].x + w0.y*xr4[tt+1].x + w0.z*xr4[tt+2].x + w0.w*xr4[tt+3].x
               + w1.x*xr4[tt].y + w1.y*xr4[tt+1].y + w1.z*xr4[tt+2].y + w1.w*xr4[tt+3].y
               + w2.x*xr4[tt].z + w2.y*xr4[tt+1].z + w2.z*xr4[tt+2].z + w2.w*xr4[tt+3].z
               + w3.x*xr4[tt].w + w3.y*xr4[tt+1].w + w3.z*xr4[tt+2].w + w3.w*xr4[tt+3].w;
    }
  }
  float cbo = cb[o];
  #pragma unroll
  for(int tt=0;tt<8;tt++){
    float y = acc[tt]+cbo;
    xt[(size_t)((b<<8)+t0+tt)*D2z+o] = y*sigmoidf_(y);
  }
}

// ---------------- o-gate (Wo, sigmoid) + v (block-diag Wv): 4 rows, 2 o/thread ----------------
__global__ void __launch_bounds__(256) k_wov(const float* __restrict__ xl,
                      const float* __restrict__ Wo,
                      const float* __restrict__ bo,const float* __restrict__ Wv,
                      float* __restrict__ og,float* __restrict__ vv){
  __shared__ float xs[4][D2z];
  int r0=blockIdx.x*4; int tid=threadIdx.x;   // 256
  for(int idx=tid;idx<512;idx+=256)
    ((float4*)&xs[0][0])[idx]=((const float4*)(xl+(size_t)r0*D2z))[idx];
  __syncthreads();
  int o0=tid,o1=tid+256;
  float a0[4]={0,0,0,0},a1[4]={0,0,0,0};
  const float4* w0=(const float4*)(Wo+(size_t)o0*D2z);
  const float4* w1=(const float4*)(Wo+(size_t)o1*D2z);
  #pragma unroll 2
  for(int i4=0;i4<128;i4++){
    float4 wa=w0[i4],wb=w1[i4];
    #pragma unroll
    for(int tt=0;tt<4;tt++){
      float4 xv=((const float4*)xs[tt])[i4];
      a0[tt]+=dot4(wa,xv); a1[tt]+=dot4(wb,xv);
    }
  }
  float v0[4]={0,0,0,0},v1[4]={0,0,0,0};
  int h0=o0>>7,h1=o1>>7;
  const float4* wv0=(const float4*)Wv+(size_t)o0*32;
  const float4* wv1=(const float4*)Wv+(size_t)o1*32;
  #pragma unroll 2
  for(int i4=0;i4<32;i4++){
    float4 wa=wv0[i4],wb=wv1[i4];
    #pragma unroll
    for(int tt=0;tt<4;tt++){
      float4 xva=((const float4*)xs[tt])[h0*32+i4];
      float4 xvb=((const float4*)xs[tt])[h1*32+i4];
      v0[tt]+=dot4(wa,xva); v1[tt]+=dot4(wb,xvb);
    }
  }
  float bo0=bo[o0],bo1=bo[o1];
  #pragma unroll
  for(int tt=0;tt<4;tt++){
    size_t row=r0+tt;
    og[row*D2z+o0]=sigmoidf_(a0[tt]+bo0);
    og[row*D2z+o1]=sigmoidf_(a1[tt]+bo1);
    vv[row*D2z+o0]=v0[tt];
    vv[row*D2z+o1]=v1[tt];
  }
}

// ---------------- q,k (block-diag) + skip GEMM from x_trans ----------------
__global__ void __launch_bounds__(256) k_qks(const float* __restrict__ xt,
                      const float* __restrict__ Wq,
                      const float* __restrict__ Wk,const float* __restrict__ SW,
                      float* __restrict__ qq,float* __restrict__ kk,
                      float* __restrict__ sk){
  __shared__ float xs[4][D2z];
  int r0=blockIdx.x*4; int tid=threadIdx.x;   // 256
  for(int idx=tid;idx<512;idx+=256)
    ((float4*)&xs[0][0])[idx]=((const float4*)(xt+(size_t)r0*D2z))[idx];
  __syncthreads();
  int o0=tid,o1=tid+256;
  float s0[4]={0,0,0,0},s1[4]={0,0,0,0};
  const float4* w0=(const float4*)(SW+(size_t)o0*D2z);
  const float4* w1=(const float4*)(SW+(size_t)o1*D2z);
  #pragma unroll 2
  for(int i4=0;i4<128;i4++){
    float4 wa=w0[i4],wb=w1[i4];
    #pragma unroll
    for(int tt=0;tt<4;tt++){
      float4 xv=((const float4*)xs[tt])[i4];
      s0[tt]+=dot4(wa,xv); s1[tt]+=dot4(wb,xv);
    }
  }
  float q0[4]={0,0,0,0},q1[4]={0,0,0,0},k0[4]={0,0,0,0},k1[4]={0,0,0,0};
  int h0=o0>>7,h1=o1>>7;
  const float4* wq0=(const float4*)Wq+(size_t)o0*32; const float4* wq1=(const float4*)Wq+(size_t)o1*32;
  const float4* wk0=(const float4*)Wk+(size_t)o0*32; const float4* wk1=(const float4*)Wk+(size_t)o1*32;
  #pragma unroll 2
  for(int i4=0;i4<32;i4++){
    float4 qa=wq0[i4],qb=wq1[i4],ka=wk0[i4],kb2=wk1[i4];
    #pragma unroll
    for(int tt=0;tt<4;tt++){
      float4 xva=((const float4*)xs[tt])[h0*32+i4];
      float4 xvb=((const float4*)xs[tt])[h1*32+i4];
      q0[tt]+=dot4(qa,xva); q1[tt]+=dot4(qb,xvb);
      k0[tt]+=dot4(ka,xva); k1[tt]+=dot4(kb2,xvb);
    }
  }
  #pragma unroll
  for(int tt=0;tt<4;tt++){
    size_t row=r0+tt;
    qq[row*D2z+o0]=q0[tt];        qq[row*D2z+o1]=q1[tt];
    kk[row*D2z+o0]=0.0625f*k0[tt]; kk[row*D2z+o1]=0.0625f*k1[tt];  // SCALE = D^-0.5
    sk[row*D2z+o0]=s0[tt];        sk[row*D2z+o1]=s1[tt];
  }
}

// ---------------- decay precompute: F = cumsum(fb), G = ib - F, Mx = max(0, cummax(G)) ----------------
__global__ void __launch_bounds__(256) k_decay(
    const float* __restrict__ ibar, const float* __restrict__ fbar,
    float* __restrict__ G, float* __restrict__ Mx){
  int b = blockIdx.x, t = threadIdx.x;   // 256 threads = Tz
  __shared__ float buf[Tz];
  float f = fbar[b*Tz + t];
  buf[t] = f; __syncthreads();
  float v = f;
  for (int off=1; off<Tz; off<<=1){
    float add = (t >= off) ? buf[t-off] : 0.f;
    __syncthreads();
    v += add; buf[t] = v;
    __syncthreads();
  }
  float F = v;
  float g = ibar[b*Tz+t] - F;
  G[b*Tz+t] = g;
  buf[t] = g; __syncthreads();
  v = g;
  for (int off=1; off<Tz; off<<=1){
    float other = (t >= off) ? buf[t-off] : -3.4e38f;
    __syncthreads();
    v = fmaxf(v, other); buf[t] = v;
    __syncthreads();
  }
  Mx[b*Tz+t] = fmaxf(v, 0.f);
}

// ---------------- scan as causal decayed attention ----------------
#define TTa 8
__global__ void __launch_bounds__(256) k_attn(
    const float* __restrict__ qq, const float* __restrict__ kk,
    const float* __restrict__ vv, const float* __restrict__ og,
    const float* __restrict__ G, const float* __restrict__ Mx,
    float* __restrict__ hs){
  int b  = blockIdx.y;
  int t0 = blockIdx.x * TTa;
  int tid = threadIdx.x;            // 256
  __shared__ float Qs[TTa][D2z];    // 16 KB
  __shared__ float Ps[TTa][Tz];     // 8 KB
  __shared__ float Gs[Tz];          // 1 KB
  __shared__ float inv_d[TTa];
  __shared__ float mxs[TTa];

  const float* qb = qq + ((size_t)b*Tz + t0)*D2z;
  for (int idx=tid; idx<TTa*D2z/4; idx+=256)
    ((float4*)&Qs[0][0])[idx] = ((const float4*)qb)[idx];
  Gs[tid] = G[b*Tz + tid];
  if (tid < TTa) mxs[tid] = Mx[b*Tz + t0 + tid];
  __syncthreads();

  int s = tid;
  int smax = t0 + TTa - 1;
  {
    float acc[TTa] = {0,0,0,0,0,0,0,0};
    if (s <= smax){
      const float4* kp = (const float4*)(kk + ((size_t)b*Tz + s)*D2z);
      for (int k4=0; k4<D2z/4; k4++){
        float4 kv = kp[k4];
        #pragma unroll
        for (int tt=0; tt<TTa; tt++){
          float4 qv = ((const float4*)Qs[tt])[k4];
          acc[tt] += dot4(kv,qv);
        }
      }
    }
    float g = Gs[s];
    #pragma unroll
    for (int tt=0; tt<TTa; tt++){
      int t = t0 + tt;
      Ps[tt][s] = (s <= t) ? acc[tt] * __expf(g - mxs[tt]) : 0.f;
    }
  }
  __syncthreads();
  {
    int wv = tid >> 6, lane = tid & 63;
    #pragma unroll
    for (int r=0; r<2; r++){
      int tt = wv*2 + r;
      float ssum = Ps[tt][lane] + Ps[tt][lane+64] + Ps[tt][lane+128] + Ps[tt][lane+192];
      #pragma unroll
      for (int off=1; off<64; off<<=1) ssum += __shfl_xor(ssum, off);
      if (lane==0) inv_d[tt] = 1.f / (fmaxf(fabsf(ssum), 1.f) + 1e-8f);
    }
  }
  __syncthreads();
  {
    int c0 = tid, c1 = tid + 256;
    float a0[TTa]={0,0,0,0,0,0,0,0}, a1[TTa]={0,0,0,0,0,0,0,0};
    const float* vb = vv + (size_t)b*Tz*D2z;
    for (int s2=0; s2<=smax; s2+=4){
      float4 pr[TTa];
      #pragma unroll
      for (int tt=0; tt<TTa; tt++) pr[tt] = *(const float4*)&Ps[tt][s2];
      #pragma unroll
      for (int j=0; j<4; j++){
        int sj = s2 + j;
        float v0 = vb[(size_t)sj*D2z + c0];
        float v1 = vb[(size_t)sj*D2z + c1];
        #pragma unroll
        for (int tt=0; tt<TTa; tt++){
          float p = ((const float*)&pr[tt])[j];
          a0[tt] += p*v0; a1[tt] += p*v1;
        }
      }
    }
    #pragma unroll
    for (int tt=0; tt<TTa; tt++){
      size_t row = (size_t)b*Tz + t0 + tt;
      float id = inv_d[tt];
      hs[row*D2z + c0] = og[row*D2z + c0] * a0[tt] * id;
      hs[row*D2z + c1] = og[row*D2z + c1] * a1[tt] * id;
    }
  }
}

// ---------------- GroupNorm stats per (b,h): mean & rstd over (T,DH) ----------------
__global__ void k_gnstat(const float* __restrict__ hs,float* __restrict__ gmu,
                         float* __restrict__ grs){
  int g=blockIdx.x; int b=g>>2,h=g&3; int tid=threadIdx.x;  // 256 thr
  float s=0.f,s2=0.f;
  const float* base=hs+(size_t)b*Tz*D2z+h*DHz;
  for(int idx=tid;idx<Tz*DHz;idx+=256){
    int t=idx>>7,c=idx&127;
    float v=base[(size_t)t*D2z+c];
    s+=v;s2+=v*v;
  }
  #pragma unroll
  for(int off=32;off;off>>=1){s+=__shfl_down(s,off);s2+=__shfl_down(s2,off);}
  __shared__ float ls[8];
  int wid=tid>>6,lane=tid&63;
  if(lane==0){ls[wid]=s;ls[4+wid]=s2;}
  __syncthreads();
  if(tid==0){
    float S=ls[0]+ls[1]+ls[2]+ls[3],S2=ls[4]+ls[5]+ls[6]+ls[7];
    float mu=S*(1.f/(Tz*DHz));
    float var=S2*(1.f/(Tz*DHz))-mu*mu;
    gmu[g]=mu; grs[g]=rsqrtf(fmaxf(var,0.f)+1e-5f);
  }
}

// ---------------- finish: GN apply + skip + *swish(x_right) + W_last GEMM + residual ----------------
__global__ void __launch_bounds__(256) k_final(const float* __restrict__ hs,
    const float* __restrict__ gmu,
    const float* __restrict__ grs,const float* __restrict__ gng,
    const float* __restrict__ gnb,const float* __restrict__ sk,
    const float* __restrict__ xr,const float* __restrict__ WL,
    const float* __restrict__ bl,const float* __restrict__ x,
    float* __restrict__ out){
  __shared__ float hm[4][D2z];
  int r0=blockIdx.x*4; int b=r0>>8; int tid=threadIdx.x;   // 256 thr
  for(int idx=tid;idx<4*D2z;idx+=256){
    int tt=idx>>9,c=idx&511;
    size_t row=r0+tt;
    int g=(b<<2)+(c>>7);
    float v=hs[row*D2z+c];
    float hg=(v-gmu[g])*grs[g]*gng[c]+gnb[c]+sk[row*D2z+c];
    float xv=xr[row*D2z+c];
    hm[tt][c]=hg*(xv*sigmoidf_(xv));
  }
  __syncthreads();
  int d=tid;
  float acc[4]={0,0,0,0};
  const float4* w4=(const float4*)(WL+(size_t)d*D2z);
  #pragma unroll 2
  for(int i4=0;i4<128;i4++){
    float4 w=w4[i4];
    #pragma unroll
    for(int tt=0;tt<4;tt++){
      float4 hv=((const float4*)hm[tt])[i4];
      acc[tt]+=dot4(w,hv);
    }
  }
  float bd=bl[d];
  #pragma unroll
  for(int tt=0;tt<4;tt++){
    size_t row=r0+tt;
    out[row*Dz+d]=acc[tt]+bd+x[row*Dz+d];
  }
}

extern "C" void kernel_launch(void* const* d_in, const int* in_sizes, int n_in,
                              void* d_out, int out_size, void* d_ws, size_t ws_size,
                              hipStream_t stream) {
  (void)in_sizes; (void)n_in; (void)out_size; (void)ws_size;
  const float* x      = (const float*)d_in[0];
  const float* ln_g   = (const float*)d_in[1];
  const float* ln_b   = (const float*)d_in[2];
  const float* W_left = (const float*)d_in[3];
  const float* b_left = (const float*)d_in[4];
  const float* W_right= (const float*)d_in[5];
  const float* b_right= (const float*)d_in[6];
  const float* Wi     = (const float*)d_in[7];
  const float* bi     = (const float*)d_in[8];
  const float* Wf     = (const float*)d_in[9];
  const float* bf     = (const float*)d_in[10];
  const float* Wo     = (const float*)d_in[11];
  const float* bo     = (const float*)d_in[12];
  const float* Wq     = (const float*)d_in[13];
  const float* Wk     = (const float*)d_in[14];
  const float* Wv     = (const float*)d_in[15];
  const float* conv_w = (const float*)d_in[16];
  const float* conv_b = (const float*)d_in[17];
  const float* skip_W = (const float*)d_in[18];
  const float* gn_g   = (const float*)d_in[19];
  const float* gn_b   = (const float*)d_in[20];
  const float* W_last = (const float*)d_in[21];
  const float* b_last = (const float*)d_in[22];
  float* out = (float*)d_out;

  float* ws = (float*)d_ws;
  float* xl   = ws + 262144;         // 524288
  float* xr   = ws + 786432;         // 524288
  float* xt   = ws + 1310720;        // 524288
  float* og   = ws + 1835008;        // 524288
  float* vv   = ws + 2359296;        // 524288
  float* qq   = ws + 2883584;        // 524288
  float* kk   = ws + 3407872;        // 524288
  float* sk   = ws + 3932160;        // 524288
  float* hs   = ws + 4456448;        // 524288
  float* ibar = ws + 4980736;        // 1024
  float* fbar = ws + 4981760;        // 1024
  float* gmu  = ws + 4982784;        // 16
  float* grs  = ws + 4982800;        // 16
  float* Gd   = ws + 4982816;        // 1024
  float* Mxd  = ws + 4983840;        // 1024

  k_lnlr  <<<BT/8, 512, 0, stream>>>(x, ln_g, ln_b, W_left, b_left, W_right, b_right, xl, xr);
  k_if    <<<BT, 64, 0, stream>>>(xl, Wi, bi, Wf, bf, ibar, fbar);
  k_decay <<<Bz, 256, 0, stream>>>(ibar, fbar, Gd, Mxd);
  k_conv  <<<dim3(BT/8, 2), 256, 0, stream>>>(xl, conv_w, conv_b, xt);
  k_wov   <<<BT/4, 256, 0, stream>>>(xl, Wo, bo, Wv, og, vv);
  k_qks   <<<BT/4, 256, 0, stream>>>(xt, Wq, Wk, skip_W, qq, kk, sk);
  k_attn  <<<dim3(Tz/TTa, Bz), 256, 0, stream>>>(qq, kk, vv, og, Gd, Mxd, hs);
  k_gnstat<<<Bz*Hz, 256, 0, stream>>>(hs, gmu, grs);
  k_final <<<BT/4, 256, 0, stream>>>(hs, gmu, grs, gn_g, gn_b, sk, xr, W_last, b_last, x, out);
}

// Round 4
// 309.269 us; speedup vs baseline: 1.2166x; 1.0672x over previous
//
#include <hip/hip_runtime.h>
#include <hip/hip_bf16.h>
#include <cstdint>

// Sizes
#define Bz 4
#define Tz 256
#define Dz 256
#define D2z 512
#define Hz 4
#define DHz 128
#define BT (Bz*Tz)          // 1024 rows

__device__ __forceinline__ float dot4(float4 a, float4 b){
  return a.x*b.x + a.y*b.y + a.z*b.z + a.w*b.w;
}
__device__ __forceinline__ float sigmoidf_(float z){ return 1.f/(1.f+__expf(-z)); }

// ---------------- fused LayerNorm + x_left/x_right GEMM + i_bar/f_bar: 8 rows, 512 thr ----------------
__global__ void __launch_bounds__(512) k_lnlr(
    const float* __restrict__ x, const float* __restrict__ lg,
    const float* __restrict__ lb, const float* __restrict__ WL,
    const float* __restrict__ bL, const float* __restrict__ WR,
    const float* __restrict__ bR,
    const float* __restrict__ Wi, const float* __restrict__ bi,
    const float* __restrict__ Wf, const float* __restrict__ bf,
    float* __restrict__ xl, float* __restrict__ xr,
    float* __restrict__ ib, float* __restrict__ fb){
  __shared__ float xs[8][Dz];
  __shared__ float rif[2][8][8];    // [i/f][wave][row]
  int r0 = blockIdx.x*8;
  int tid = threadIdx.x;            // 512
  ((float4*)&xs[0][0])[tid] = ((const float4*)(x + (size_t)r0*Dz))[tid];
  __syncthreads();
  // wave w normalizes row w (256 elems, 4/lane)
  int w = tid>>6, lane = tid&63;
  float a0 = xs[w][lane],     a1 = xs[w][lane+64];
  float a2 = xs[w][lane+128], a3 = xs[w][lane+192];
  float s  = a0+a1+a2+a3;
  float s2 = a0*a0+a1*a1+a2*a2+a3*a3;
  #pragma unroll
  for (int off=1; off<64; off<<=1){ s += __shfl_xor(s, off); s2 += __shfl_xor(s2, off); }
  float mu = s*(1.f/Dz);
  float rs = rsqrtf(s2*(1.f/Dz)-mu*mu+1e-5f);
  xs[w][lane]     = (a0-mu)*rs*lg[lane]    +lb[lane];
  xs[w][lane+64]  = (a1-mu)*rs*lg[lane+64] +lb[lane+64];
  xs[w][lane+128] = (a2-mu)*rs*lg[lane+128]+lb[lane+128];
  xs[w][lane+192] = (a3-mu)*rs*lg[lane+192]+lb[lane+192];
  __syncthreads();
  int o = tid;
  float accL[8]={0,0,0,0,0,0,0,0}, accR[8]={0,0,0,0,0,0,0,0};
  const float4* wl4 = (const float4*)(WL + (size_t)o*Dz);
  const float4* wr4 = (const float4*)(WR + (size_t)o*Dz);
  #pragma unroll 2
  for (int k4=0;k4<Dz/4;k4++){
    float4 wl=wl4[k4], wr=wr4[k4];
    #pragma unroll
    for(int tt=0;tt<8;tt++){
      float4 xv = ((const float4*)xs[tt])[k4];
      accL[tt] += dot4(wl,xv);
      accR[tt] += dot4(wr,xv);
    }
  }
  float bl=bL[o], br=bR[o];
  float wi_o=Wi[o], wf_o=Wf[o];
  #pragma unroll
  for(int tt=0;tt<8;tt++){
    float xlv = accL[tt]+bl;
    xl[(size_t)(r0+tt)*D2z+o]=xlv;
    xr[(size_t)(r0+tt)*D2z+o]=accR[tt]+br;
    accL[tt]=xlv*wi_o;              // reuse regs: i_bar partials
    accR[tt]=xlv*wf_o;              // f_bar partials
  }
  #pragma unroll
  for(int off=1;off<64;off<<=1){
    #pragma unroll
    for(int tt=0;tt<8;tt++){
      accL[tt]+=__shfl_xor(accL[tt],off);
      accR[tt]+=__shfl_xor(accR[tt],off);
    }
  }
  if(lane==0){
    #pragma unroll
    for(int tt=0;tt<8;tt++){ rif[0][w][tt]=accL[tt]; rif[1][w][tt]=accR[tt]; }
  }
  __syncthreads();
  if(tid<16){
    int r=tid&7, which=tid>>3;
    float sv=0.f;
    #pragma unroll
    for(int ww=0;ww<8;ww++) sv+=rif[which][ww][r];
    if(which==0) ib[r0+r]=sv+bi[0]; else fb[r0+r]=sv+bf[0];
  }
}

// ---------------- causal conv1d k=4 + swish ----------------
// Block = 256 thr = (64 out-chans x 4 ic-chunks of 128). Grid = (128 t-tiles, 8 out-groups)
// = 1024 blocks -> 4 blocks/CU, in-block LDS reduce over ic-chunks (no global partials).
__global__ void __launch_bounds__(256) k_conv(const float* __restrict__ xl,
                       const float* __restrict__ CW,
                       const float* __restrict__ cb, float* __restrict__ xt){
  __shared__ float xs[11][D2z];     // 22528 B: rows t0-3 .. t0+7
  __shared__ float red[4][64][9];   // 9216 B (pad 9 -> 2-way bank alias, free)
  int tb = blockIdx.x;              // 0..127
  int b = tb>>5; int t0 = (tb&31)*8;
  int o0 = blockIdx.y*64;           // 0..7 -> 64-output group
  int tid = threadIdx.x;            // 256
  for(int idx=tid; idx<11*(D2z/4); idx+=256){
    int j = idx>>7;                 // row 0..10 (128 float4 per row)
    int k4 = idx&127;
    int t = t0-3+j;
    float4 v = (t>=0) ? ((const float4*)(xl + (size_t)((b<<8)+t)*D2z))[k4]
                      : make_float4(0.f,0.f,0.f,0.f);
    ((float4*)xs[j])[k4]=v;
  }
  __syncthreads();
  int ol = tid&63, ch = tid>>6;     // wave == one ic-chunk -> xs reads broadcast
  int o = o0 + ol, ic0 = ch*128;
  float acc[8]={0,0,0,0,0,0,0,0};
  const float4* w4 = (const float4*)(CW + (size_t)o*2048) + ic0;  // taps 0..3 per chan
  #pragma unroll 2
  for(int i=0;i<128;i+=4){
    float4 w0=w4[i], w1=w4[i+1], w2=w4[i+2], w3=w4[i+3];
    float4 xr4[11];
    #pragma unroll
    for(int j=0;j<11;j++) xr4[j]=*(const float4*)&xs[j][ic0+i];
    #pragma unroll
    for(int tt=0;tt<8;tt++){
      acc[tt] += w0.x*xr4[tt].x + w0.y*xr4[tt+1].x + w0.z*xr4[tt+2].x + w0.w*xr4[tt+3].x
               + w1.x*xr4[tt].y + w1.y*xr4[tt+1].y + w1.z*xr4[tt+2].y + w1.w*xr4[tt+3].y
               + w2.x*xr4[tt].z + w2.y*xr4[tt+1].z + w2.z*xr4[tt+2].z + w2.w*xr4[tt+3].z
               + w3.x*xr4[tt].w + w3.y*xr4[tt+1].w + w3.z*xr4[tt+2].w + w3.w*xr4[tt+3].w;
    }
  }
  #pragma unroll
  for(int tt=0;tt<8;tt++) red[ch][ol][tt]=acc[tt];
  __syncthreads();
  #pragma unroll
  for(int idx=tid; idx<512; idx+=256){
    int oo = idx&63, t = idx>>6;    // lanes consecutive in oo -> coalesced stores
    float y = red[0][oo][t]+red[1][oo][t]+red[2][oo][t]+red[3][oo][t] + cb[o0+oo];
    xt[(size_t)((b<<8)+t0+t)*D2z + o0+oo] = y*sigmoidf_(y);
  }
}

// ---------------- o-gate (Wo, sigmoid) + v (block-diag Wv): 4 rows, 2 o/thread ----------------
__global__ void __launch_bounds__(256) k_wov(const float* __restrict__ xl,
                      const float* __restrict__ Wo,
                      const float* __restrict__ bo,const float* __restrict__ Wv,
                      float* __restrict__ og,float* __restrict__ vv){
  __shared__ float xs[4][D2z];
  int r0=blockIdx.x*4; int tid=threadIdx.x;   // 256
  for(int idx=tid;idx<512;idx+=256)
    ((float4*)&xs[0][0])[idx]=((const float4*)(xl+(size_t)r0*D2z))[idx];
  __syncthreads();
  int o0=tid,o1=tid+256;
  float a0[4]={0,0,0,0},a1[4]={0,0,0,0};
  const float4* w0=(const float4*)(Wo+(size_t)o0*D2z);
  const float4* w1=(const float4*)(Wo+(size_t)o1*D2z);
  #pragma unroll 2
  for(int i4=0;i4<128;i4++){
    float4 wa=w0[i4],wb=w1[i4];
    #pragma unroll
    for(int tt=0;tt<4;tt++){
      float4 xv=((const float4*)xs[tt])[i4];
      a0[tt]+=dot4(wa,xv); a1[tt]+=dot4(wb,xv);
    }
  }
  float v0[4]={0,0,0,0},v1[4]={0,0,0,0};
  int h0=o0>>7,h1=o1>>7;
  const float4* wv0=(const float4*)Wv+(size_t)o0*32;
  const float4* wv1=(const float4*)Wv+(size_t)o1*32;
  #pragma unroll 2
  for(int i4=0;i4<32;i4++){
    float4 wa=wv0[i4],wb=wv1[i4];
    #pragma unroll
    for(int tt=0;tt<4;tt++){
      float4 xva=((const float4*)xs[tt])[h0*32+i4];
      float4 xvb=((const float4*)xs[tt])[h1*32+i4];
      v0[tt]+=dot4(wa,xva); v1[tt]+=dot4(wb,xvb);
    }
  }
  float bo0=bo[o0],bo1=bo[o1];
  #pragma unroll
  for(int tt=0;tt<4;tt++){
    size_t row=r0+tt;
    og[row*D2z+o0]=sigmoidf_(a0[tt]+bo0);
    og[row*D2z+o1]=sigmoidf_(a1[tt]+bo1);
    vv[row*D2z+o0]=v0[tt];
    vv[row*D2z+o1]=v1[tt];
  }
}

// ---------------- q,k (block-diag) + skip GEMM from x_trans ----------------
__global__ void __launch_bounds__(256) k_qks(const float* __restrict__ xt,
                      const float* __restrict__ Wq,
                      const float* __restrict__ Wk,const float* __restrict__ SW,
                      float* __restrict__ qq,float* __restrict__ kk,
                      float* __restrict__ sk){
  __shared__ float xs[4][D2z];
  int r0=blockIdx.x*4; int tid=threadIdx.x;   // 256
  for(int idx=tid;idx<512;idx+=256)
    ((float4*)&xs[0][0])[idx]=((const float4*)(xt+(size_t)r0*D2z))[idx];
  __syncthreads();
  int o0=tid,o1=tid+256;
  float s0[4]={0,0,0,0},s1[4]={0,0,0,0};
  const float4* w0=(const float4*)(SW+(size_t)o0*D2z);
  const float4* w1=(const float4*)(SW+(size_t)o1*D2z);
  #pragma unroll 2
  for(int i4=0;i4<128;i4++){
    float4 wa=w0[i4],wb=w1[i4];
    #pragma unroll
    for(int tt=0;tt<4;tt++){
      float4 xv=((const float4*)xs[tt])[i4];
      s0[tt]+=dot4(wa,xv); s1[tt]+=dot4(wb,xv);
    }
  }
  float q0[4]={0,0,0,0},q1[4]={0,0,0,0},k0[4]={0,0,0,0},k1[4]={0,0,0,0};
  int h0=o0>>7,h1=o1>>7;
  const float4* wq0=(const float4*)Wq+(size_t)o0*32; const float4* wq1=(const float4*)Wq+(size_t)o1*32;
  const float4* wk0=(const float4*)Wk+(size_t)o0*32; const float4* wk1=(const float4*)Wk+(size_t)o1*32;
  #pragma unroll 2
  for(int i4=0;i4<32;i4++){
    float4 qa=wq0[i4],qb=wq1[i4],ka=wk0[i4],kb2=wk1[i4];
    #pragma unroll
    for(int tt=0;tt<4;tt++){
      float4 xva=((const float4*)xs[tt])[h0*32+i4];
      float4 xvb=((const float4*)xs[tt])[h1*32+i4];
      q0[tt]+=dot4(qa,xva); q1[tt]+=dot4(qb,xvb);
      k0[tt]+=dot4(ka,xva); k1[tt]+=dot4(kb2,xvb);
    }
  }
  #pragma unroll
  for(int tt=0;tt<4;tt++){
    size_t row=r0+tt;
    qq[row*D2z+o0]=q0[tt];        qq[row*D2z+o1]=q1[tt];
    kk[row*D2z+o0]=0.0625f*k0[tt]; kk[row*D2z+o1]=0.0625f*k1[tt];  // SCALE = D^-0.5
    sk[row*D2z+o0]=s0[tt];        sk[row*D2z+o1]=s1[tt];
  }
}

// ---------------- decay precompute: F = cumsum(fb), G = ib - F, Mx = max(0, cummax(G)) ----------------
__global__ void __launch_bounds__(256) k_decay(
    const float* __restrict__ ibar, const float* __restrict__ fbar,
    float* __restrict__ G, float* __restrict__ Mx){
  int b = blockIdx.x, t = threadIdx.x;   // 256 threads = Tz
  __shared__ float buf[Tz];
  float f = fbar[b*Tz + t];
  buf[t] = f; __syncthreads();
  float v = f;
  for (int off=1; off<Tz; off<<=1){
    float add = (t >= off) ? buf[t-off] : 0.f;
    __syncthreads();
    v += add; buf[t] = v;
    __syncthreads();
  }
  float F = v;
  float g = ibar[b*Tz+t] - F;
  G[b*Tz+t] = g;
  buf[t] = g; __syncthreads();
  v = g;
  for (int off=1; off<Tz; off<<=1){
    float other = (t >= off) ? buf[t-off] : -3.4e38f;
    __syncthreads();
    v = fmaxf(v, other); buf[t] = v;
    __syncthreads();
  }
  Mx[b*Tz+t] = fmaxf(v, 0.f);
}

// ---------------- scan as causal decayed attention ----------------
#define TTa 8
__global__ void __launch_bounds__(256) k_attn(
    const float* __restrict__ qq, const float* __restrict__ kk,
    const float* __restrict__ vv, const float* __restrict__ og,
    const float* __restrict__ G, const float* __restrict__ Mx,
    float* __restrict__ hs){
  int b  = blockIdx.y;
  int t0 = blockIdx.x * TTa;
  int tid = threadIdx.x;            // 256
  __shared__ float Qs[TTa][D2z];    // 16 KB
  __shared__ float Ps[TTa][Tz];     // 8 KB
  __shared__ float Gs[Tz];          // 1 KB
  __shared__ float inv_d[TTa];
  __shared__ float mxs[TTa];

  const float* qb = qq + ((size_t)b*Tz + t0)*D2z;
  for (int idx=tid; idx<TTa*D2z/4; idx+=256)
    ((float4*)&Qs[0][0])[idx] = ((const float4*)qb)[idx];
  Gs[tid] = G[b*Tz + tid];
  if (tid < TTa) mxs[tid] = Mx[b*Tz + t0 + tid];
  __syncthreads();

  int s = tid;
  int smax = t0 + TTa - 1;
  {
    float acc[TTa] = {0,0,0,0,0,0,0,0};
    if (s <= smax){
      const float4* kp = (const float4*)(kk + ((size_t)b*Tz + s)*D2z);
      for (int k4=0; k4<D2z/4; k4++){
        float4 kv = kp[k4];
        #pragma unroll
        for (int tt=0; tt<TTa; tt++){
          float4 qv = ((const float4*)Qs[tt])[k4];
          acc[tt] += dot4(kv,qv);
        }
      }
    }
    float g = Gs[s];
    #pragma unroll
    for (int tt=0; tt<TTa; tt++){
      int t = t0 + tt;
      Ps[tt][s] = (s <= t) ? acc[tt] * __expf(g - mxs[tt]) : 0.f;
    }
  }
  __syncthreads();
  {
    int wv = tid >> 6, lane = tid & 63;
    #pragma unroll
    for (int r=0; r<2; r++){
      int tt = wv*2 + r;
      float ssum = Ps[tt][lane] + Ps[tt][lane+64] + Ps[tt][lane+128] + Ps[tt][lane+192];
      #pragma unroll
      for (int off=1; off<64; off<<=1) ssum += __shfl_xor(ssum, off);
      if (lane==0) inv_d[tt] = 1.f / (fmaxf(fabsf(ssum), 1.f) + 1e-8f);
    }
  }
  __syncthreads();
  {
    int c0 = tid, c1 = tid + 256;
    float a0[TTa]={0,0,0,0,0,0,0,0}, a1[TTa]={0,0,0,0,0,0,0,0};
    const float* vb = vv + (size_t)b*Tz*D2z;
    for (int s2=0; s2<=smax; s2+=4){
      float4 pr[TTa];
      #pragma unroll
      for (int tt=0; tt<TTa; tt++) pr[tt] = *(const float4*)&Ps[tt][s2];
      #pragma unroll
      for (int j=0; j<4; j++){
        int sj = s2 + j;
        float v0 = vb[(size_t)sj*D2z + c0];
        float v1 = vb[(size_t)sj*D2z + c1];
        #pragma unroll
        for (int tt=0; tt<TTa; tt++){
          float p = ((const float*)&pr[tt])[j];
          a0[tt] += p*v0; a1[tt] += p*v1;
        }
      }
    }
    #pragma unroll
    for (int tt=0; tt<TTa; tt++){
      size_t row = (size_t)b*Tz + t0 + tt;
      float id = inv_d[tt];
      hs[row*D2z + c0] = og[row*D2z + c0] * a0[tt] * id;
      hs[row*D2z + c1] = og[row*D2z + c1] * a1[tt] * id;
    }
  }
}

// ---------------- GroupNorm stats per (b,h): mean & rstd over (T,DH) ----------------
__global__ void k_gnstat(const float* __restrict__ hs,float* __restrict__ gmu,
                         float* __restrict__ grs){
  int g=blockIdx.x; int b=g>>2,h=g&3; int tid=threadIdx.x;  // 256 thr
  float s=0.f,s2=0.f;
  const float* base=hs+(size_t)b*Tz*D2z+h*DHz;
  for(int idx=tid;idx<Tz*DHz;idx+=256){
    int t=idx>>7,c=idx&127;
    float v=base[(size_t)t*D2z+c];
    s+=v;s2+=v*v;
  }
  #pragma unroll
  for(int off=32;off;off>>=1){s+=__shfl_down(s,off);s2+=__shfl_down(s2,off);}
  __shared__ float ls[8];
  int wid=tid>>6,lane=tid&63;
  if(lane==0){ls[wid]=s;ls[4+wid]=s2;}
  __syncthreads();
  if(tid==0){
    float S=ls[0]+ls[1]+ls[2]+ls[3],S2=ls[4]+ls[5]+ls[6]+ls[7];
    float mu=S*(1.f/(Tz*DHz));
    float var=S2*(1.f/(Tz*DHz))-mu*mu;
    gmu[g]=mu; grs[g]=rsqrtf(fmaxf(var,0.f)+1e-5f);
  }
}

// ---------------- finish: GN apply + skip + *swish(x_right) + W_last GEMM + residual ----------------
__global__ void __launch_bounds__(256) k_final(const float* __restrict__ hs,
    const float* __restrict__ gmu,
    const float* __restrict__ grs,const float* __restrict__ gng,
    const float* __restrict__ gnb,const float* __restrict__ sk,
    const float* __restrict__ xr,const float* __restrict__ WL,
    const float* __restrict__ bl,const float* __restrict__ x,
    float* __restrict__ out){
  __shared__ float hm[4][D2z];
  int r0=blockIdx.x*4; int b=r0>>8; int tid=threadIdx.x;   // 256 thr
  for(int idx=tid;idx<4*D2z;idx+=256){
    int tt=idx>>9,c=idx&511;
    size_t row=r0+tt;
    int g=(b<<2)+(c>>7);
    float v=hs[row*D2z+c];
    float hg=(v-gmu[g])*grs[g]*gng[c]+gnb[c]+sk[row*D2z+c];
    float xv=xr[row*D2z+c];
    hm[tt][c]=hg*(xv*sigmoidf_(xv));
  }
  __syncthreads();
  int d=tid;
  float acc[4]={0,0,0,0};
  const float4* w4=(const float4*)(WL+(size_t)d*D2z);
  #pragma unroll 2
  for(int i4=0;i4<128;i4++){
    float4 w=w4[i4];
    #pragma unroll
    for(int tt=0;tt<4;tt++){
      float4 hv=((const float4*)hm[tt])[i4];
      acc[tt]+=dot4(w,hv);
    }
  }
  float bd=bl[d];
  #pragma unroll
  for(int tt=0;tt<4;tt++){
    size_t row=r0+tt;
    out[row*Dz+d]=acc[tt]+bd+x[row*Dz+d];
  }
}

extern "C" void kernel_launch(void* const* d_in, const int* in_sizes, int n_in,
                              void* d_out, int out_size, void* d_ws, size_t ws_size,
                              hipStream_t stream) {
  (void)in_sizes; (void)n_in; (void)out_size; (void)ws_size;
  const float* x      = (const float*)d_in[0];
  const float* ln_g   = (const float*)d_in[1];
  const float* ln_b   = (const float*)d_in[2];
  const float* W_left = (const float*)d_in[3];
  const float* b_left = (const float*)d_in[4];
  const float* W_right= (const float*)d_in[5];
  const float* b_right= (const float*)d_in[6];
  const float* Wi     = (const float*)d_in[7];
  const float* bi     = (const float*)d_in[8];
  const float* Wf     = (const float*)d_in[9];
  const float* bf     = (const float*)d_in[10];
  const float* Wo     = (const float*)d_in[11];
  const float* bo     = (const float*)d_in[12];
  const float* Wq     = (const float*)d_in[13];
  const float* Wk     = (const float*)d_in[14];
  const float* Wv     = (const float*)d_in[15];
  const float* conv_w = (const float*)d_in[16];
  const float* conv_b = (const float*)d_in[17];
  const float* skip_W = (const float*)d_in[18];
  const float* gn_g   = (const float*)d_in[19];
  const float* gn_b   = (const float*)d_in[20];
  const float* W_last = (const float*)d_in[21];
  const float* b_last = (const float*)d_in[22];
  float* out = (float*)d_out;

  float* ws = (float*)d_ws;
  float* xl   = ws + 262144;         // 524288
  float* xr   = ws + 786432;         // 524288
  float* xt   = ws + 1310720;        // 524288
  float* og   = ws + 1835008;        // 524288
  float* vv   = ws + 2359296;        // 524288
  float* qq   = ws + 2883584;        // 524288
  float* kk   = ws + 3407872;        // 524288
  float* sk   = ws + 3932160;        // 524288
  float* hs   = ws + 4456448;        // 524288
  float* ibar = ws + 4980736;        // 1024
  float* fbar = ws + 4981760;        // 1024
  float* gmu  = ws + 4982784;        // 16
  float* grs  = ws + 4982800;        // 16
  float* Gd   = ws + 4982816;        // 1024
  float* Mxd  = ws + 4983840;        // 1024

  k_lnlr  <<<BT/8, 512, 0, stream>>>(x, ln_g, ln_b, W_left, b_left, W_right, b_right,
                                     Wi, bi, Wf, bf, xl, xr, ibar, fbar);
  k_decay <<<Bz, 256, 0, stream>>>(ibar, fbar, Gd, Mxd);
  k_conv  <<<dim3(BT/8, 8), 256, 0, stream>>>(xl, conv_w, conv_b, xt);
  k_wov   <<<BT/4, 256, 0, stream>>>(xl, Wo, bo, Wv, og, vv);
  k_qks   <<<BT/4, 256, 0, stream>>>(xt, Wq, Wk, skip_W, qq, kk, sk);
  k_attn  <<<dim3(Tz/TTa, Bz), 256, 0, stream>>>(qq, kk, vv, og, Gd, Mxd, hs);
  k_gnstat<<<Bz*Hz, 256, 0, stream>>>(hs, gmu, grs);
  k_final <<<BT/4, 256, 0, stream>>>(hs, gmu, grs, gn_g, gn_b, sk, xr, W_last, b_last, x, out);
}

// Round 5
// 286.008 us; speedup vs baseline: 1.3155x; 1.0813x over previous
//
#include <hip/hip_runtime.h>
#include <hip/hip_bf16.h>
#include <cstdint>

// Sizes
#define Bz 4
#define Tz 256
#define Dz 256
#define D2z 512
#define Hz 4
#define DHz 128
#define BT (Bz*Tz)          // 1024 rows

__device__ __forceinline__ float dot4(float4 a, float4 b){
  return a.x*b.x + a.y*b.y + a.z*b.z + a.w*b.w;
}
__device__ __forceinline__ float sigmoidf_(float z){ return 1.f/(1.f+__expf(-z)); }

// ---------------- fused LayerNorm + x_left/x_right GEMM + i/f partials ----------------
// grid (BT/8, 2 out-halves), 512 thr. which=tid>>8 picks WL or WR; o = oh*256+(tid&255).
__global__ void __launch_bounds__(512,2) k_lnlr(
    const float* __restrict__ x, const float* __restrict__ lg,
    const float* __restrict__ lb, const float* __restrict__ WL,
    const float* __restrict__ bL, const float* __restrict__ WR,
    const float* __restrict__ bR,
    const float* __restrict__ Wi, const float* __restrict__ bi,
    const float* __restrict__ Wf, const float* __restrict__ bf,
    float* __restrict__ xl, float* __restrict__ xr,
    float* __restrict__ ibp, float* __restrict__ fbp){
  __shared__ float xs[8][Dz];
  __shared__ float rif[2][4][8];    // [i/f][wave 0-3][row]
  int r0 = blockIdx.x*8; int oh = blockIdx.y;
  int tid = threadIdx.x;            // 512
  ((float4*)&xs[0][0])[tid] = ((const float4*)(x + (size_t)r0*Dz))[tid];
  __syncthreads();
  // wave w normalizes row w
  int w = tid>>6, lane = tid&63;
  float a0 = xs[w][lane],     a1 = xs[w][lane+64];
  float a2 = xs[w][lane+128], a3 = xs[w][lane+192];
  float s  = a0+a1+a2+a3;
  float s2 = a0*a0+a1*a1+a2*a2+a3*a3;
  #pragma unroll
  for (int off=1; off<64; off<<=1){ s += __shfl_xor(s, off); s2 += __shfl_xor(s2, off); }
  float mu = s*(1.f/Dz);
  float rs = rsqrtf(s2*(1.f/Dz)-mu*mu+1e-5f);
  xs[w][lane]     = (a0-mu)*rs*lg[lane]    +lb[lane];
  xs[w][lane+64]  = (a1-mu)*rs*lg[lane+64] +lb[lane+64];
  xs[w][lane+128] = (a2-mu)*rs*lg[lane+128]+lb[lane+128];
  xs[w][lane+192] = (a3-mu)*rs*lg[lane+192]+lb[lane+192];
  __syncthreads();
  int which = tid>>8;               // 0 -> WL (+i/f), 1 -> WR
  int o = oh*256 + (tid&255);
  float acc[8]={0,0,0,0,0,0,0,0};
  const float* WM = which ? WR : WL;
  const float4* wm4 = (const float4*)(WM + (size_t)o*Dz);
  #pragma unroll 2
  for (int k4=0;k4<Dz/4;k4++){
    float4 wv=wm4[k4];
    #pragma unroll
    for(int tt=0;tt<8;tt++) acc[tt] += dot4(wv, ((const float4*)xs[tt])[k4]);
  }
  if (which==0){
    float blv=bL[o], wi_o=Wi[o], wf_o=Wf[o];
    float pi[8], pf[8];
    #pragma unroll
    for(int tt=0;tt<8;tt++){
      float xlv = acc[tt]+blv;
      xl[(size_t)(r0+tt)*D2z+o]=xlv;
      pi[tt]=xlv*wi_o; pf[tt]=xlv*wf_o;
    }
    #pragma unroll
    for(int off=1;off<64;off<<=1){
      #pragma unroll
      for(int tt=0;tt<8;tt++){ pi[tt]+=__shfl_xor(pi[tt],off); pf[tt]+=__shfl_xor(pf[tt],off); }
    }
    if(lane==0){
      #pragma unroll
      for(int tt=0;tt<8;tt++){ rif[0][w][tt]=pi[tt]; rif[1][w][tt]=pf[tt]; }
    }
  } else {
    float brv=bR[o];
    #pragma unroll
    for(int tt=0;tt<8;tt++) xr[(size_t)(r0+tt)*D2z+o]=acc[tt]+brv;
  }
  __syncthreads();
  if(tid<16){
    int r=tid&7, which2=tid>>3;
    float sv=0.f;
    #pragma unroll
    for(int ww=0;ww<4;ww++) sv+=rif[which2][ww][r];
    float bias = (oh==0) ? (which2==0 ? bi[0] : bf[0]) : 0.f;
    (which2==0 ? ibp : fbp)[oh*BT + r0 + r] = sv + bias;
  }
}

// ---------------- causal conv1d k=4 + swish ----------------
// Block = 256 thr = (64 out-chans x 4 ic-chunks of 128). Grid = (128 t-tiles, 8 out-groups).
// launch_bounds(256,4): VGPR cap 128 so the 11x b128 LDS reads + weights can stay pipelined.
__global__ void __launch_bounds__(256,4) k_conv(const float* __restrict__ xl,
                       const float* __restrict__ CW,
                       const float* __restrict__ cb, float* __restrict__ xt){
  __shared__ float xs[11][D2z];     // 22528 B
  __shared__ float red[4][64][9];   // 9216 B
  int tb = blockIdx.x;              // 0..127
  int b = tb>>5; int t0 = (tb&31)*8;
  int o0 = blockIdx.y*64;
  int tid = threadIdx.x;            // 256
  for(int idx=tid; idx<11*(D2z/4); idx+=256){
    int j = idx>>7;
    int k4 = idx&127;
    int t = t0-3+j;
    float4 v = (t>=0) ? ((const float4*)(xl + (size_t)((b<<8)+t)*D2z))[k4]
                      : make_float4(0.f,0.f,0.f,0.f);
    ((float4*)xs[j])[k4]=v;
  }
  __syncthreads();
  int ol = tid&63, ch = tid>>6;
  int o = o0 + ol, ic0 = ch*128;
  float acc[8]={0,0,0,0,0,0,0,0};
  const float4* w4 = (const float4*)(CW + (size_t)o*2048) + ic0;
  #pragma unroll 2
  for(int i=0;i<128;i+=4){
    float4 w0=w4[i], w1=w4[i+1], w2=w4[i+2], w3=w4[i+3];
    float4 xr4[11];
    #pragma unroll
    for(int j=0;j<11;j++) xr4[j]=*(const float4*)&xs[j][ic0+i];
    #pragma unroll
    for(int tt=0;tt<8;tt++){
      acc[tt] += w0.x*xr4[tt].x + w0.y*xr4[tt+1].x + w0.z*xr4[tt+2].x + w0.w*xr4[tt+3].x
               + w1.x*xr4[tt].y + w1.y*xr4[tt+1].y + w1.z*xr4[tt+2].y + w1.w*xr4[tt+3].y
               + w2.x*xr4[tt].z + w2.y*xr4[tt+1].z + w2.z*xr4[tt+2].z + w2.w*xr4[tt+3].z
               + w3.x*xr4[tt].w + w3.y*xr4[tt+1].w + w3.z*xr4[tt+2].w + w3.w*xr4[tt+3].w;
    }
  }
  #pragma unroll
  for(int tt=0;tt<8;tt++) red[ch][ol][tt]=acc[tt];
  __syncthreads();
  #pragma unroll
  for(int idx=tid; idx<512; idx+=256){
    int oo = idx&63, t = idx>>6;
    float y = red[0][oo][t]+red[1][oo][t]+red[2][oo][t]+red[3][oo][t] + cb[o0+oo];
    xt[(size_t)((b<<8)+t0+t)*D2z + o0+oo] = y*sigmoidf_(y);
  }
}

// ---------------- o-gate + v: 256 thr = 64 outs x 4 ic-chunks, grid (BT/4, 8) ----------------
__global__ void __launch_bounds__(256,4) k_wov(const float* __restrict__ xl,
                      const float* __restrict__ Wo,
                      const float* __restrict__ bo,const float* __restrict__ Wv,
                      float* __restrict__ og,float* __restrict__ vv){
  __shared__ float xs[4][D2z];
  __shared__ float red[4][64][5];
  int r0=blockIdx.x*4; int ogp=blockIdx.y; int tid=threadIdx.x;
  for(int idx=tid;idx<512;idx+=256)
    ((float4*)&xs[0][0])[idx]=((const float4*)(xl+(size_t)r0*D2z))[idx];
  __syncthreads();
  int ol=tid&63, ch=tid>>6;
  int o = ogp*64+ol;
  float a[4]={0,0,0,0};
  const float4* w4=(const float4*)(Wo+(size_t)o*D2z) + ch*32;
  #pragma unroll 2
  for(int i4=0;i4<32;i4++){
    float4 w=w4[i4];
    #pragma unroll
    for(int tt=0;tt<4;tt++) a[tt]+=dot4(w, ((const float4*)xs[tt])[ch*32+i4]);
  }
  #pragma unroll
  for(int tt=0;tt<4;tt++) red[ch][ol][tt]=a[tt];
  int h = ogp>>1;                   // head of this o-group; its ic slice == chunk h
  if(ch==h){
    float v[4]={0,0,0,0};
    const float4* wv4=(const float4*)Wv + (size_t)o*32;
    #pragma unroll 2
    for(int i4=0;i4<32;i4++){
      float4 w=wv4[i4];
      #pragma unroll
      for(int tt=0;tt<4;tt++) v[tt]+=dot4(w, ((const float4*)xs[tt])[h*32+i4]);
    }
    #pragma unroll
    for(int tt=0;tt<4;tt++) vv[(size_t)(r0+tt)*D2z+o]=v[tt];
  }
  __syncthreads();
  {
    int oo=tid&63, t=tid>>6;
    float sv=red[0][oo][t]+red[1][oo][t]+red[2][oo][t]+red[3][oo][t];
    og[(size_t)(r0+t)*D2z+ogp*64+oo]=sigmoidf_(sv+bo[ogp*64+oo]);
  }
}

// ---------------- q,k (block-diag) + skip GEMM: same chunked shape ----------------
__global__ void __launch_bounds__(256,4) k_qks(const float* __restrict__ xt,
                      const float* __restrict__ Wq,
                      const float* __restrict__ Wk,const float* __restrict__ SW,
                      float* __restrict__ qq,float* __restrict__ kk,
                      float* __restrict__ sk){
  __shared__ float xs[4][D2z];
  __shared__ float red[4][64][5];
  int r0=blockIdx.x*4; int ogp=blockIdx.y; int tid=threadIdx.x;
  for(int idx=tid;idx<512;idx+=256)
    ((float4*)&xs[0][0])[idx]=((const float4*)(xt+(size_t)r0*D2z))[idx];
  __syncthreads();
  int ol=tid&63, ch=tid>>6;
  int o = ogp*64+ol;
  float a[4]={0,0,0,0};
  const float4* w4=(const float4*)(SW+(size_t)o*D2z) + ch*32;
  #pragma unroll 2
  for(int i4=0;i4<32;i4++){
    float4 w=w4[i4];
    #pragma unroll
    for(int tt=0;tt<4;tt++) a[tt]+=dot4(w, ((const float4*)xs[tt])[ch*32+i4]);
  }
  #pragma unroll
  for(int tt=0;tt<4;tt++) red[ch][ol][tt]=a[tt];
  int h = ogp>>1;
  if(ch==h){
    float q[4]={0,0,0,0},k[4]={0,0,0,0};
    const float4* wq4=(const float4*)Wq + (size_t)o*32;
    const float4* wk4=(const float4*)Wk + (size_t)o*32;
    #pragma unroll 2
    for(int i4=0;i4<32;i4++){
      float4 qa=wq4[i4], ka=wk4[i4];
      #pragma unroll
      for(int tt=0;tt<4;tt++){
        float4 xv=((const float4*)xs[tt])[h*32+i4];
        q[tt]+=dot4(qa,xv); k[tt]+=dot4(ka,xv);
      }
    }
    #pragma unroll
    for(int tt=0;tt<4;tt++){
      qq[(size_t)(r0+tt)*D2z+o]=q[tt];
      kk[(size_t)(r0+tt)*D2z+o]=0.0625f*k[tt];   // SCALE = D^-0.5
    }
  }
  __syncthreads();
  {
    int oo=tid&63, t=tid>>6;
    float sv=red[0][oo][t]+red[1][oo][t]+red[2][oo][t]+red[3][oo][t];
    sk[(size_t)(r0+t)*D2z+ogp*64+oo]=sv;
  }
}

// ---------------- decay precompute (now sums the two i/f partial halves) ----------------
__global__ void __launch_bounds__(256) k_decay(
    const float* __restrict__ ibp, const float* __restrict__ fbp,
    float* __restrict__ G, float* __restrict__ Mx){
  int b = blockIdx.x, t = threadIdx.x;
  __shared__ float buf[Tz];
  float f = fbp[b*Tz + t] + fbp[BT + b*Tz + t];
  float ibv = ibp[b*Tz + t] + ibp[BT + b*Tz + t];
  buf[t] = f; __syncthreads();
  float v = f;
  for (int off=1; off<Tz; off<<=1){
    float add = (t >= off) ? buf[t-off] : 0.f;
    __syncthreads();
    v += add; buf[t] = v;
    __syncthreads();
  }
  float F = v;
  float g = ibv - F;
  G[b*Tz+t] = g;
  buf[t] = g; __syncthreads();
  v = g;
  for (int off=1; off<Tz; off<<=1){
    float other = (t >= off) ? buf[t-off] : -3.4e38f;
    __syncthreads();
    v = fmaxf(v, other); buf[t] = v;
    __syncthreads();
  }
  Mx[b*Tz+t] = fmaxf(v, 0.f);
}

// ---------------- scan as causal decayed attention: TTa=4, grid (64, B) ----------------
#define TTa 4
__global__ void __launch_bounds__(256) k_attn(
    const float* __restrict__ qq, const float* __restrict__ kk,
    const float* __restrict__ vv, const float* __restrict__ og,
    const float* __restrict__ G, const float* __restrict__ Mx,
    float* __restrict__ hs){
  int b  = blockIdx.y;
  int t0 = blockIdx.x * TTa;
  int tid = threadIdx.x;            // 256
  __shared__ float Qs[TTa][D2z];    // 8 KB
  __shared__ float Ps[TTa][Tz];     // 4 KB
  __shared__ float Gs[Tz];          // 1 KB
  __shared__ float inv_d[TTa];
  __shared__ float mxs[TTa];

  const float* qb = qq + ((size_t)b*Tz + t0)*D2z;
  for (int idx=tid; idx<TTa*D2z/4; idx+=256)
    ((float4*)&Qs[0][0])[idx] = ((const float4*)qb)[idx];
  Gs[tid] = G[b*Tz + tid];
  if (tid < TTa) mxs[tid] = Mx[b*Tz + t0 + tid];
  __syncthreads();

  int s = tid;
  int smax = t0 + TTa - 1;
  {
    float acc[TTa] = {0,0,0,0};
    if (s <= smax){
      const float4* kp = (const float4*)(kk + ((size_t)b*Tz + s)*D2z);
      for (int k4=0; k4<D2z/4; k4++){
        float4 kv = kp[k4];
        #pragma unroll
        for (int tt=0; tt<TTa; tt++){
          float4 qv = ((const float4*)Qs[tt])[k4];
          acc[tt] += dot4(kv,qv);
        }
      }
    }
    float g = Gs[s];
    #pragma unroll
    for (int tt=0; tt<TTa; tt++){
      int t = t0 + tt;
      Ps[tt][s] = (s <= t) ? acc[tt] * __expf(g - mxs[tt]) : 0.f;
    }
  }
  __syncthreads();
  {
    int wv = tid >> 6, lane = tid & 63;
    int tt = wv;                    // 4 waves <-> 4 rows
    float ssum = Ps[tt][lane] + Ps[tt][lane+64] + Ps[tt][lane+128] + Ps[tt][lane+192];
    #pragma unroll
    for (int off=1; off<64; off<<=1) ssum += __shfl_xor(ssum, off);
    if (lane==0) inv_d[tt] = 1.f / (fmaxf(fabsf(ssum), 1.f) + 1e-8f);
  }
  __syncthreads();
  {
    int c0 = tid, c1 = tid + 256;
    float a0[TTa]={0,0,0,0}, a1[TTa]={0,0,0,0};
    const float* vb = vv + (size_t)b*Tz*D2z;
    for (int s2=0; s2<=smax; s2+=4){
      float4 pr[TTa];
      #pragma unroll
      for (int tt=0; tt<TTa; tt++) pr[tt] = *(const float4*)&Ps[tt][s2];
      #pragma unroll
      for (int j=0; j<4; j++){
        int sj = s2 + j;
        float v0 = vb[(size_t)sj*D2z + c0];
        float v1 = vb[(size_t)sj*D2z + c1];
        #pragma unroll
        for (int tt=0; tt<TTa; tt++){
          float p = ((const float*)&pr[tt])[j];
          a0[tt] += p*v0; a1[tt] += p*v1;
        }
      }
    }
    #pragma unroll
    for (int tt=0; tt<TTa; tt++){
      size_t row = (size_t)b*Tz + t0 + tt;
      float id = inv_d[tt];
      hs[row*D2z + c0] = og[row*D2z + c0] * a0[tt] * id;
      hs[row*D2z + c1] = og[row*D2z + c1] * a1[tt] * id;
    }
  }
}

// ---------------- GroupNorm stats per (b,h) ----------------
__global__ void k_gnstat(const float* __restrict__ hs,float* __restrict__ gmu,
                         float* __restrict__ grs){
  int g=blockIdx.x; int b=g>>2,h=g&3; int tid=threadIdx.x;
  float s=0.f,s2=0.f;
  const float* base=hs+(size_t)b*Tz*D2z+h*DHz;
  for(int idx=tid;idx<Tz*DHz;idx+=256){
    int t=idx>>7,c=idx&127;
    float v=base[(size_t)t*D2z+c];
    s+=v;s2+=v*v;
  }
  #pragma unroll
  for(int off=32;off;off>>=1){s+=__shfl_down(s,off);s2+=__shfl_down(s2,off);}
  __shared__ float ls[8];
  int wid=tid>>6,lane=tid&63;
  if(lane==0){ls[wid]=s;ls[4+wid]=s2;}
  __syncthreads();
  if(tid==0){
    float S=ls[0]+ls[1]+ls[2]+ls[3],S2=ls[4]+ls[5]+ls[6]+ls[7];
    float mu=S*(1.f/(Tz*DHz));
    float var=S2*(1.f/(Tz*DHz))-mu*mu;
    gmu[g]=mu; grs[g]=rsqrtf(fmaxf(var,0.f)+1e-5f);
  }
}

// ---------------- finish: chunked W_last GEMM, grid (BT/4, 4) ----------------
__global__ void __launch_bounds__(256,4) k_final(const float* __restrict__ hs,
    const float* __restrict__ gmu,
    const float* __restrict__ grs,const float* __restrict__ gng,
    const float* __restrict__ gnb,const float* __restrict__ sk,
    const float* __restrict__ xr,const float* __restrict__ WL,
    const float* __restrict__ bl,const float* __restrict__ x,
    float* __restrict__ out){
  __shared__ float hm[4][D2z];
  __shared__ float red[4][64][5];
  int r0=blockIdx.x*4; int b=r0>>8; int ogp=blockIdx.y; int tid=threadIdx.x;
  for(int idx=tid;idx<4*D2z;idx+=256){
    int tt=idx>>9,c=idx&511;
    size_t row=r0+tt;
    int g=(b<<2)+(c>>7);
    float v=hs[row*D2z+c];
    float hg=(v-gmu[g])*grs[g]*gng[c]+gnb[c]+sk[row*D2z+c];
    float xv=xr[row*D2z+c];
    hm[tt][c]=hg*(xv*sigmoidf_(xv));
  }
  __syncthreads();
  int ol=tid&63, ch=tid>>6;
  int d=ogp*64+ol;
  float acc[4]={0,0,0,0};
  const float4* w4=(const float4*)(WL+(size_t)d*D2z)+ch*32;
  #pragma unroll 2
  for(int i4=0;i4<32;i4++){
    float4 w=w4[i4];
    #pragma unroll
    for(int tt=0;tt<4;tt++) acc[tt]+=dot4(w,((const float4*)hm[tt])[ch*32+i4]);
  }
  #pragma unroll
  for(int tt=0;tt<4;tt++) red[ch][ol][tt]=acc[tt];
  __syncthreads();
  {
    int oo=tid&63, t=tid>>6;
    int d2=ogp*64+oo;
    float sv=red[0][oo][t]+red[1][oo][t]+red[2][oo][t]+red[3][oo][t];
    size_t row=r0+t;
    out[row*Dz+d2]=sv+bl[d2]+x[row*Dz+d2];
  }
}

extern "C" void kernel_launch(void* const* d_in, const int* in_sizes, int n_in,
                              void* d_out, int out_size, void* d_ws, size_t ws_size,
                              hipStream_t stream) {
  (void)in_sizes; (void)n_in; (void)out_size; (void)ws_size;
  const float* x      = (const float*)d_in[0];
  const float* ln_g   = (const float*)d_in[1];
  const float* ln_b   = (const float*)d_in[2];
  const float* W_left = (const float*)d_in[3];
  const float* b_left = (const float*)d_in[4];
  const float* W_right= (const float*)d_in[5];
  const float* b_right= (const float*)d_in[6];
  const float* Wi     = (const float*)d_in[7];
  const float* bi     = (const float*)d_in[8];
  const float* Wf     = (const float*)d_in[9];
  const float* bf     = (const float*)d_in[10];
  const float* Wo     = (const float*)d_in[11];
  const float* bo     = (const float*)d_in[12];
  const float* Wq     = (const float*)d_in[13];
  const float* Wk     = (const float*)d_in[14];
  const float* Wv     = (const float*)d_in[15];
  const float* conv_w = (const float*)d_in[16];
  const float* conv_b = (const float*)d_in[17];
  const float* skip_W = (const float*)d_in[18];
  const float* gn_g   = (const float*)d_in[19];
  const float* gn_b   = (const float*)d_in[20];
  const float* W_last = (const float*)d_in[21];
  const float* b_last = (const float*)d_in[22];
  float* out = (float*)d_out;

  float* ws = (float*)d_ws;
  float* xl   = ws + 262144;         // 524288
  float* xr   = ws + 786432;         // 524288
  float* xt   = ws + 1310720;        // 524288
  float* og   = ws + 1835008;        // 524288
  float* vv   = ws + 2359296;        // 524288
  float* qq   = ws + 2883584;        // 524288
  float* kk   = ws + 3407872;        // 524288
  float* sk   = ws + 3932160;        // 524288
  float* hs   = ws + 4456448;        // 524288
  float* ibp  = ws + 4980736;        // 2048 (two halves)
  float* fbp  = ws + 4982784;        // 2048
  float* gmu  = ws + 4984832;        // 16
  float* grs  = ws + 4984848;        // 16
  float* Gd   = ws + 4984864;        // 1024
  float* Mxd  = ws + 4985888;        // 1024

  k_lnlr  <<<dim3(BT/8, 2), 512, 0, stream>>>(x, ln_g, ln_b, W_left, b_left, W_right, b_right,
                                              Wi, bi, Wf, bf, xl, xr, ibp, fbp);
  k_decay <<<Bz, 256, 0, stream>>>(ibp, fbp, Gd, Mxd);
  k_conv  <<<dim3(BT/8, 8), 256, 0, stream>>>(xl, conv_w, conv_b, xt);
  k_wov   <<<dim3(BT/4, 8), 256, 0, stream>>>(xl, Wo, bo, Wv, og, vv);
  k_qks   <<<dim3(BT/4, 8), 256, 0, stream>>>(xt, Wq, Wk, skip_W, qq, kk, sk);
  k_attn  <<<dim3(Tz/TTa, Bz), 256, 0, stream>>>(qq, kk, vv, og, Gd, Mxd, hs);
  k_gnstat<<<Bz*Hz, 256, 0, stream>>>(hs, gmu, grs);
  k_final <<<dim3(BT/4, 4), 256, 0, stream>>>(hs, gmu, grs, gn_g, gn_b, sk, xr, W_last, b_last, x, out);
}

// Round 6
// 207.494 us; speedup vs baseline: 1.8133x; 1.3784x over previous
//
#include <hip/hip_runtime.h>
#include <hip/hip_bf16.h>
#include <cstdint>

// Sizes
#define Bz 4
#define Tz 256
#define Dz 256
#define D2z 512
#define Hz 4
#define DHz 128
#define BT (Bz*Tz)          // 1024 rows

__device__ __forceinline__ float dot4(float4 a, float4 b){
  return a.x*b.x + a.y*b.y + a.z*b.z + a.w*b.w;
}
__device__ __forceinline__ float sigmoidf_(float z){ return 1.f/(1.f+__expf(-z)); }
__device__ __forceinline__ float4 fma4(float4 a, float4 w, float s){
  a.x += w.x*s; a.y += w.y*s; a.z += w.z*s; a.w += w.w*s; return a;
}
__device__ __forceinline__ float4 add4(float4 a, float4 b){
  a.x+=b.x; a.y+=b.y; a.z+=b.z; a.w+=b.w; return a;
}

// ---------------- one-shot weight transposes ----------------
// [0,64) Wo 512x512 -> Wot[k][o]; [64,128) SW; [128,160) W_last 256x512 -> WLt[k][o(256)]
// [160,208) Wq/Wk/Wv per-head 128x128 -> [h][id][od]; [208,464) conv_w as float4 512x512 -> CWt[i][o]
__global__ void __launch_bounds__(256) k_tr(
    const float* __restrict__ Wo, const float* __restrict__ SW,
    const float* __restrict__ Wl, const float* __restrict__ Wq,
    const float* __restrict__ Wk, const float* __restrict__ Wv,
    const float* __restrict__ CW,
    float* __restrict__ Wot, float* __restrict__ SWt, float* __restrict__ WLt,
    float* __restrict__ Wqt, float* __restrict__ Wkt, float* __restrict__ Wvt,
    float* __restrict__ CWt){
  int bid = blockIdx.x, tid = threadIdx.x;
  if (bid < 208){
    __shared__ float ts[64][65];
    const float* src; float* dst; int O,K,to,tk;
    if (bid<64){ src=Wo; dst=Wot; O=512;K=512; to=bid>>3; tk=bid&7; }
    else if (bid<128){ int r=bid-64; src=SW; dst=SWt; O=512;K=512; to=r>>3; tk=r&7; }
    else if (bid<160){ int r=bid-128; src=Wl; dst=WLt; O=256;K=512; to=r>>3; tk=r&7; }
    else {
      int r=bid-160; int m=r>>4; int rr=r&15; int h=rr>>2; int s=rr&3;
      src=(m==0?Wq:m==1?Wk:Wv) + h*16384;
      dst=(m==0?Wqt:m==1?Wkt:Wvt) + h*16384;
      O=128; K=128; to=s>>1; tk=s&1;
    }
    int lk=tid&63, ro=tid>>6;
    #pragma unroll
    for(int p=0;p<16;p++) ts[p*4+ro][lk] = src[(size_t)(to*64+p*4+ro)*K + tk*64+lk];
    __syncthreads();
    #pragma unroll
    for(int p=0;p<16;p++) dst[(size_t)(tk*64+p*4+ro)*O + to*64+lk] = ts[lk][p*4+ro];
  } else {
    __shared__ float4 t4[32][33];
    int r = bid-208; int to=r>>4, tk=r&15;
    const float4* src4=(const float4*)CW; float4* dst4=(float4*)CWt;
    int li=tid&31, ro=tid>>5;
    #pragma unroll
    for(int p=0;p<4;p++) t4[p*8+ro][li] = src4[(size_t)(to*32+p*8+ro)*512 + tk*32+li];
    __syncthreads();
    #pragma unroll
    for(int p=0;p<4;p++) dst4[(size_t)(tk*32+p*8+ro)*512 + to*32+li] = t4[li][p*8+ro];
  }
}

// ---------------- fused LayerNorm + x_left/x_right GEMM + i/f partials ----------------
__global__ void __launch_bounds__(512,2) k_lnlr(
    const float* __restrict__ x, const float* __restrict__ lg,
    const float* __restrict__ lb, const float* __restrict__ WL,
    const float* __restrict__ bL, const float* __restrict__ WR,
    const float* __restrict__ bR,
    const float* __restrict__ Wi, const float* __restrict__ bi,
    const float* __restrict__ Wf, const float* __restrict__ bf,
    float* __restrict__ xl, float* __restrict__ xr,
    float* __restrict__ ibp, float* __restrict__ fbp){
  __shared__ float xs[8][Dz];
  __shared__ float rif[2][4][8];    // [i/f][wave 0-3][row]
  int r0 = blockIdx.x*8; int oh = blockIdx.y;
  int tid = threadIdx.x;            // 512
  ((float4*)&xs[0][0])[tid] = ((const float4*)(x + (size_t)r0*Dz))[tid];
  __syncthreads();
  int w = tid>>6, lane = tid&63;
  float a0 = xs[w][lane],     a1 = xs[w][lane+64];
  float a2 = xs[w][lane+128], a3 = xs[w][lane+192];
  float s  = a0+a1+a2+a3;
  float s2 = a0*a0+a1*a1+a2*a2+a3*a3;
  #pragma unroll
  for (int off=1; off<64; off<<=1){ s += __shfl_xor(s, off); s2 += __shfl_xor(s2, off); }
  float mu = s*(1.f/Dz);
  float rs = rsqrtf(s2*(1.f/Dz)-mu*mu+1e-5f);
  xs[w][lane]     = (a0-mu)*rs*lg[lane]    +lb[lane];
  xs[w][lane+64]  = (a1-mu)*rs*lg[lane+64] +lb[lane+64];
  xs[w][lane+128] = (a2-mu)*rs*lg[lane+128]+lb[lane+128];
  xs[w][lane+192] = (a3-mu)*rs*lg[lane+192]+lb[lane+192];
  __syncthreads();
  int which = tid>>8;               // 0 -> WL (+i/f), 1 -> WR
  int o = oh*256 + (tid&255);
  float acc[8]={0,0,0,0,0,0,0,0};
  const float* WM = which ? WR : WL;
  const float4* wm4 = (const float4*)(WM + (size_t)o*Dz);
  #pragma unroll 2
  for (int k4=0;k4<Dz/4;k4++){
    float4 wv=wm4[k4];
    #pragma unroll
    for(int tt=0;tt<8;tt++) acc[tt] += dot4(wv, ((const float4*)xs[tt])[k4]);
  }
  if (which==0){
    float blv=bL[o], wi_o=Wi[o], wf_o=Wf[o];
    float pi[8], pf[8];
    #pragma unroll
    for(int tt=0;tt<8;tt++){
      float xlv = acc[tt]+blv;
      xl[(size_t)(r0+tt)*D2z+o]=xlv;
      pi[tt]=xlv*wi_o; pf[tt]=xlv*wf_o;
    }
    #pragma unroll
    for(int off=1;off<64;off<<=1){
      #pragma unroll
      for(int tt=0;tt<8;tt++){ pi[tt]+=__shfl_xor(pi[tt],off); pf[tt]+=__shfl_xor(pf[tt],off); }
    }
    if(lane==0){
      #pragma unroll
      for(int tt=0;tt<8;tt++){ rif[0][w][tt]=pi[tt]; rif[1][w][tt]=pf[tt]; }
    }
  } else {
    float brv=bR[o];
    #pragma unroll
    for(int tt=0;tt<8;tt++) xr[(size_t)(r0+tt)*D2z+o]=acc[tt]+brv;
  }
  __syncthreads();
  if(tid<16){
    int r=tid&7, which2=tid>>3;
    float sv=0.f;
    #pragma unroll
    for(int ww=0;ww<4;ww++) sv+=rif[which2][ww][r];
    float bias = (oh==0) ? (which2==0 ? bi[0] : bf[0]) : 0.f;
    (which2==0 ? ibp : fbp)[oh*BT + r0 + r] = sv + bias;
  }
}

// ---------------- causal conv1d k=4 + swish (coalesced transposed weights) ----------------
__global__ void __launch_bounds__(256,4) k_conv(const float* __restrict__ xl,
                       const float* __restrict__ CWt,
                       const float* __restrict__ cb, float* __restrict__ xt){
  __shared__ float xs[11][D2z];     // 22528 B
  __shared__ float red[4][64][9];   // 9216 B
  int tb = blockIdx.x;              // 0..127
  int b = tb>>5; int t0 = (tb&31)*8;
  int o0 = blockIdx.y*64;
  int tid = threadIdx.x;            // 256
  for(int idx=tid; idx<11*(D2z/4); idx+=256){
    int j = idx>>7;
    int k4 = idx&127;
    int t = t0-3+j;
    float4 v = (t>=0) ? ((const float4*)(xl + (size_t)((b<<8)+t)*D2z))[k4]
                      : make_float4(0.f,0.f,0.f,0.f);
    ((float4*)xs[j])[k4]=v;
  }
  __syncthreads();
  int ol = tid&63, ch = tid>>6;
  int o = o0 + ol, ic0 = ch*128;
  float acc[8]={0,0,0,0,0,0,0,0};
  const float4* w4 = (const float4*)CWt + o;   // quad index [i*512 + o]
  #pragma unroll 2
  for(int i=0;i<128;i+=4){
    int ig = ic0+i;
    float4 w0=w4[(size_t)(ig+0)*512], w1=w4[(size_t)(ig+1)*512];
    float4 w2=w4[(size_t)(ig+2)*512], w3=w4[(size_t)(ig+3)*512];
    float4 xr4[11];
    #pragma unroll
    for(int j=0;j<11;j++) xr4[j]=*(const float4*)&xs[j][ig];
    #pragma unroll
    for(int tt=0;tt<8;tt++){
      acc[tt] += w0.x*xr4[tt].x + w0.y*xr4[tt+1].x + w0.z*xr4[tt+2].x + w0.w*xr4[tt+3].x
               + w1.x*xr4[tt].y + w1.y*xr4[tt+1].y + w1.z*xr4[tt+2].y + w1.w*xr4[tt+3].y
               + w2.x*xr4[tt].z + w2.y*xr4[tt+1].z + w2.z*xr4[tt+2].z + w2.w*xr4[tt+3].z
               + w3.x*xr4[tt].w + w3.y*xr4[tt+1].w + w3.z*xr4[tt+2].w + w3.w*xr4[tt+3].w;
    }
  }
  #pragma unroll
  for(int tt=0;tt<8;tt++) red[ch][ol][tt]=acc[tt];
  __syncthreads();
  #pragma unroll
  for(int idx=tid; idx<512; idx+=256){
    int oo = idx&63, t = idx>>6;
    float y = red[0][oo][t]+red[1][oo][t]+red[2][oo][t]+red[3][oo][t] + cb[o0+oo];
    xt[(size_t)((b<<8)+t0+t)*D2z + o0+oo] = y*sigmoidf_(y);
  }
}

// ---------------- o-gate + v: thread = o-quad x k-chunk, coalesced Wot/Wvt ----------------
__global__ void __launch_bounds__(256,2) k_wov(const float* __restrict__ xl,
    const float* __restrict__ Wot, const float* __restrict__ bo,
    const float* __restrict__ Wvt, float* __restrict__ og, float* __restrict__ vv){
  __shared__ float xs[4][D2z];          // 8KB
  __shared__ float4 ored[4][4][64];     // 16KB
  __shared__ float4 vred[4][4][64];     // 16KB
  int r0=blockIdx.x*4; int oh=blockIdx.y; int tid=threadIdx.x;
  for(int idx=tid;idx<512;idx+=256)
    ((float4*)&xs[0][0])[idx]=((const float4*)(xl+(size_t)r0*D2z))[idx];
  __syncthreads();
  int ol=tid&63, ch=tid>>6;
  float4 a0={0,0,0,0},a1={0,0,0,0},a2={0,0,0,0},a3={0,0,0,0};
  const float4* wp=(const float4*)Wot + (size_t)ch*16384 + (oh*64+ol);
  #pragma unroll 2
  for(int kq=0;kq<32;kq++){
    int k=ch*128+kq*4;
    float4 w0=wp[(kq*4+0)*128], w1=wp[(kq*4+1)*128], w2=wp[(kq*4+2)*128], w3=wp[(kq*4+3)*128];
    float4 x0=*(const float4*)&xs[0][k];
    float4 x1=*(const float4*)&xs[1][k];
    float4 x2=*(const float4*)&xs[2][k];
    float4 x3=*(const float4*)&xs[3][k];
    a0=fma4(fma4(fma4(fma4(a0,w0,x0.x),w1,x0.y),w2,x0.z),w3,x0.w);
    a1=fma4(fma4(fma4(fma4(a1,w0,x1.x),w1,x1.y),w2,x1.z),w3,x1.w);
    a2=fma4(fma4(fma4(fma4(a2,w0,x2.x),w1,x2.y),w2,x2.z),w3,x2.w);
    a3=fma4(fma4(fma4(fma4(a3,w0,x3.x),w1,x3.y),w2,x3.z),w3,x3.w);
  }
  ored[ch][0][ol]=a0; ored[ch][1][ol]=a1; ored[ch][2][ol]=a2; ored[ch][3][ol]=a3;
  // v block-diag, k-split across chunks: head per lane, id = ch*32 + [0,32)
  {
    int h = oh*2 + (ol>>5), odq = ol&31;
    float4 v0={0,0,0,0},v1={0,0,0,0},v2={0,0,0,0},v3={0,0,0,0};
    const float4* wv=(const float4*)Wvt + (size_t)h*4096 + (size_t)(ch*32)*32 + odq;
    int xoff = h*128 + ch*32;
    #pragma unroll 2
    for(int iq=0;iq<8;iq++){
      float4 w0=wv[(iq*4+0)*32], w1=wv[(iq*4+1)*32], w2=wv[(iq*4+2)*32], w3=wv[(iq*4+3)*32];
      float4 x0=*(const float4*)&xs[0][xoff+iq*4];
      float4 x1=*(const float4*)&xs[1][xoff+iq*4];
      float4 x2=*(const float4*)&xs[2][xoff+iq*4];
      float4 x3=*(const float4*)&xs[3][xoff+iq*4];
      v0=fma4(fma4(fma4(fma4(v0,w0,x0.x),w1,x0.y),w2,x0.z),w3,x0.w);
      v1=fma4(fma4(fma4(fma4(v1,w0,x1.x),w1,x1.y),w2,x1.z),w3,x1.w);
      v2=fma4(fma4(fma4(fma4(v2,w0,x2.x),w1,x2.y),w2,x2.z),w3,x2.w);
      v3=fma4(fma4(fma4(fma4(v3,w0,x3.x),w1,x3.y),w2,x3.z),w3,x3.w);
    }
    vred[ch][0][ol]=v0; vred[ch][1][ol]=v1; vred[ch][2][ol]=v2; vred[ch][3][ol]=v3;
  }
  __syncthreads();
  int tt=tid>>6, oo=tid&63;
  float4 s=add4(add4(ored[0][tt][oo],ored[1][tt][oo]),add4(ored[2][tt][oo],ored[3][tt][oo]));
  float4 bb=((const float4*)bo)[oh*64+oo];
  s.x=sigmoidf_(s.x+bb.x); s.y=sigmoidf_(s.y+bb.y);
  s.z=sigmoidf_(s.z+bb.z); s.w=sigmoidf_(s.w+bb.w);
  float4 vs=add4(add4(vred[0][tt][oo],vred[1][tt][oo]),add4(vred[2][tt][oo],vred[3][tt][oo]));
  size_t row=r0+tt;
  ((float4*)(og+row*D2z))[oh*64+oo]=s;
  ((float4*)(vv+row*D2z))[oh*64+oo]=vs;
}

// ---------------- q,k (block-diag) + skip GEMM, coalesced transposed weights ----------------
__global__ void __launch_bounds__(256,2) k_qks(const float* __restrict__ xt,
    const float* __restrict__ SWt, const float* __restrict__ Wqt,
    const float* __restrict__ Wkt,
    float* __restrict__ qq, float* __restrict__ kk, float* __restrict__ sk){
  __shared__ float xs[4][D2z];          // 8KB
  __shared__ float4 sred[4][4][64];     // 16KB
  __shared__ float4 qred[4][4][64];     // 16KB
  __shared__ float4 kred[4][4][64];     // 16KB
  int r0=blockIdx.x*4; int oh=blockIdx.y; int tid=threadIdx.x;
  for(int idx=tid;idx<512;idx+=256)
    ((float4*)&xs[0][0])[idx]=((const float4*)(xt+(size_t)r0*D2z))[idx];
  __syncthreads();
  int ol=tid&63, ch=tid>>6;
  float4 s0={0,0,0,0},s1={0,0,0,0},s2={0,0,0,0},s3={0,0,0,0};
  const float4* wp=(const float4*)SWt + (size_t)ch*16384 + (oh*64+ol);
  #pragma unroll 2
  for(int kq=0;kq<32;kq++){
    int k=ch*128+kq*4;
    float4 w0=wp[(kq*4+0)*128], w1=wp[(kq*4+1)*128], w2=wp[(kq*4+2)*128], w3=wp[(kq*4+3)*128];
    float4 x0=*(const float4*)&xs[0][k];
    float4 x1=*(const float4*)&xs[1][k];
    float4 x2=*(const float4*)&xs[2][k];
    float4 x3=*(const float4*)&xs[3][k];
    s0=fma4(fma4(fma4(fma4(s0,w0,x0.x),w1,x0.y),w2,x0.z),w3,x0.w);
    s1=fma4(fma4(fma4(fma4(s1,w0,x1.x),w1,x1.y),w2,x1.z),w3,x1.w);
    s2=fma4(fma4(fma4(fma4(s2,w0,x2.x),w1,x2.y),w2,x2.z),w3,x2.w);
    s3=fma4(fma4(fma4(fma4(s3,w0,x3.x),w1,x3.y),w2,x3.z),w3,x3.w);
  }
  sred[ch][0][ol]=s0; sred[ch][1][ol]=s1; sred[ch][2][ol]=s2; sred[ch][3][ol]=s3;
  {
    int h = oh*2 + (ol>>5), odq = ol&31;
    float4 q0={0,0,0,0},q1={0,0,0,0},q2={0,0,0,0},q3={0,0,0,0};
    float4 c0={0,0,0,0},c1={0,0,0,0},c2={0,0,0,0},c3={0,0,0,0};
    const float4* wq=(const float4*)Wqt + (size_t)h*4096 + (size_t)(ch*32)*32 + odq;
    const float4* wk=(const float4*)Wkt + (size_t)h*4096 + (size_t)(ch*32)*32 + odq;
    int xoff = h*128 + ch*32;
    #pragma unroll 2
    for(int iq=0;iq<8;iq++){
      float4 qa0=wq[(iq*4+0)*32], qa1=wq[(iq*4+1)*32], qa2=wq[(iq*4+2)*32], qa3=wq[(iq*4+3)*32];
      float4 ka0=wk[(iq*4+0)*32], ka1=wk[(iq*4+1)*32], ka2=wk[(iq*4+2)*32], ka3=wk[(iq*4+3)*32];
      float4 x0=*(const float4*)&xs[0][xoff+iq*4];
      float4 x1=*(const float4*)&xs[1][xoff+iq*4];
      float4 x2=*(const float4*)&xs[2][xoff+iq*4];
      float4 x3=*(const float4*)&xs[3][xoff+iq*4];
      q0=fma4(fma4(fma4(fma4(q0,qa0,x0.x),qa1,x0.y),qa2,x0.z),qa3,x0.w);
      q1=fma4(fma4(fma4(fma4(q1,qa0,x1.x),qa1,x1.y),qa2,x1.z),qa3,x1.w);
      q2=fma4(fma4(fma4(fma4(q2,qa0,x2.x),qa1,x2.y),qa2,x2.z),qa3,x2.w);
      q3=fma4(fma4(fma4(fma4(q3,qa0,x3.x),qa1,x3.y),qa2,x3.z),qa3,x3.w);
      c0=fma4(fma4(fma4(fma4(c0,ka0,x0.x),ka1,x0.y),ka2,x0.z),ka3,x0.w);
      c1=fma4(fma4(fma4(fma4(c1,ka0,x1.x),ka1,x1.y),ka2,x1.z),ka3,x1.w);
      c2=fma4(fma4(fma4(fma4(c2,ka0,x2.x),ka1,x2.y),ka2,x2.z),ka3,x2.w);
      c3=fma4(fma4(fma4(fma4(c3,ka0,x3.x),ka1,x3.y),ka2,x3.z),ka3,x3.w);
    }
    qred[ch][0][ol]=q0; qred[ch][1][ol]=q1; qred[ch][2][ol]=q2; qred[ch][3][ol]=q3;
    kred[ch][0][ol]=c0; kred[ch][1][ol]=c1; kred[ch][2][ol]=c2; kred[ch][3][ol]=c3;
  }
  __syncthreads();
  int tt=tid>>6, oo=tid&63;
  float4 sv=add4(add4(sred[0][tt][oo],sred[1][tt][oo]),add4(sred[2][tt][oo],sred[3][tt][oo]));
  float4 qv=add4(add4(qred[0][tt][oo],qred[1][tt][oo]),add4(qred[2][tt][oo],qred[3][tt][oo]));
  float4 kv=add4(add4(kred[0][tt][oo],kred[1][tt][oo]),add4(kred[2][tt][oo],kred[3][tt][oo]));
  kv.x*=0.0625f; kv.y*=0.0625f; kv.z*=0.0625f; kv.w*=0.0625f;   // SCALE = D^-0.5
  size_t row=r0+tt;
  ((float4*)(sk+row*D2z))[oh*64+oo]=sv;
  ((float4*)(qq+row*D2z))[oh*64+oo]=qv;
  ((float4*)(kk+row*D2z))[oh*64+oo]=kv;
}

// ---------------- decay precompute ----------------
__global__ void __launch_bounds__(256) k_decay(
    const float* __restrict__ ibp, const float* __restrict__ fbp,
    float* __restrict__ G, float* __restrict__ Mx){
  int b = blockIdx.x, t = threadIdx.x;
  __shared__ float buf[Tz];
  float f = fbp[b*Tz + t] + fbp[BT + b*Tz + t];
  float ibv = ibp[b*Tz + t] + ibp[BT + b*Tz + t];
  buf[t] = f; __syncthreads();
  float v = f;
  for (int off=1; off<Tz; off<<=1){
    float add = (t >= off) ? buf[t-off] : 0.f;
    __syncthreads();
    v += add; buf[t] = v;
    __syncthreads();
  }
  float F = v;
  float g = ibv - F;
  G[b*Tz+t] = g;
  buf[t] = g; __syncthreads();
  v = g;
  for (int off=1; off<Tz; off<<=1){
    float other = (t >= off) ? buf[t-off] : -3.4e38f;
    __syncthreads();
    v = fmaxf(v, other); buf[t] = v;
    __syncthreads();
  }
  Mx[b*Tz+t] = fmaxf(v, 0.f);
}

// ---------------- scan as causal decayed attention: TTa=4, grid (64, B) ----------------
#define TTa 4
__global__ void __launch_bounds__(256) k_attn(
    const float* __restrict__ qq, const float* __restrict__ kk,
    const float* __restrict__ vv, const float* __restrict__ og,
    const float* __restrict__ G, const float* __restrict__ Mx,
    float* __restrict__ hs){
  int b  = blockIdx.y;
  int t0 = blockIdx.x * TTa;
  int tid = threadIdx.x;            // 256
  __shared__ float Qs[TTa][D2z];
  __shared__ float Ps[TTa][Tz];
  __shared__ float Gs[Tz];
  __shared__ float inv_d[TTa];
  __shared__ float mxs[TTa];

  const float* qb = qq + ((size_t)b*Tz + t0)*D2z;
  for (int idx=tid; idx<TTa*D2z/4; idx+=256)
    ((float4*)&Qs[0][0])[idx] = ((const float4*)qb)[idx];
  Gs[tid] = G[b*Tz + tid];
  if (tid < TTa) mxs[tid] = Mx[b*Tz + t0 + tid];
  __syncthreads();

  int s = tid;
  int smax = t0 + TTa - 1;
  {
    float acc[TTa] = {0,0,0,0};
    if (s <= smax){
      const float4* kp = (const float4*)(kk + ((size_t)b*Tz + s)*D2z);
      for (int k4=0; k4<D2z/4; k4++){
        float4 kv = kp[k4];
        #pragma unroll
        for (int tt=0; tt<TTa; tt++){
          float4 qv = ((const float4*)Qs[tt])[k4];
          acc[tt] += dot4(kv,qv);
        }
      }
    }
    float g = Gs[s];
    #pragma unroll
    for (int tt=0; tt<TTa; tt++){
      int t = t0 + tt;
      Ps[tt][s] = (s <= t) ? acc[tt] * __expf(g - mxs[tt]) : 0.f;
    }
  }
  __syncthreads();
  {
    int wv = tid >> 6, lane = tid & 63;
    int tt = wv;
    float ssum = Ps[tt][lane] + Ps[tt][lane+64] + Ps[tt][lane+128] + Ps[tt][lane+192];
    #pragma unroll
    for (int off=1; off<64; off<<=1) ssum += __shfl_xor(ssum, off);
    if (lane==0) inv_d[tt] = 1.f / (fmaxf(fabsf(ssum), 1.f) + 1e-8f);
  }
  __syncthreads();
  {
    int c0 = tid, c1 = tid + 256;
    float a0[TTa]={0,0,0,0}, a1[TTa]={0,0,0,0};
    const float* vb = vv + (size_t)b*Tz*D2z;
    for (int s2=0; s2<=smax; s2+=4){
      float4 pr[TTa];
      #pragma unroll
      for (int tt=0; tt<TTa; tt++) pr[tt] = *(const float4*)&Ps[tt][s2];
      #pragma unroll
      for (int j=0; j<4; j++){
        int sj = s2 + j;
        float v0 = vb[(size_t)sj*D2z + c0];
        float v1 = vb[(size_t)sj*D2z + c1];
        #pragma unroll
        for (int tt=0; tt<TTa; tt++){
          float p = ((const float*)&pr[tt])[j];
          a0[tt] += p*v0; a1[tt] += p*v1;
        }
      }
    }
    #pragma unroll
    for (int tt=0; tt<TTa; tt++){
      size_t row = (size_t)b*Tz + t0 + tt;
      float id = inv_d[tt];
      hs[row*D2z + c0] = og[row*D2z + c0] * a0[tt] * id;
      hs[row*D2z + c1] = og[row*D2z + c1] * a1[tt] * id;
    }
  }
}

// ---------------- GroupNorm stats per (b,h) ----------------
__global__ void k_gnstat(const float* __restrict__ hs,float* __restrict__ gmu,
                         float* __restrict__ grs){
  int g=blockIdx.x; int b=g>>2,h=g&3; int tid=threadIdx.x;
  float s=0.f,s2=0.f;
  const float* base=hs+(size_t)b*Tz*D2z+h*DHz;
  for(int idx=tid;idx<Tz*DHz;idx+=256){
    int t=idx>>7,c=idx&127;
    float v=base[(size_t)t*D2z+c];
    s+=v;s2+=v*v;
  }
  #pragma unroll
  for(int off=32;off;off>>=1){s+=__shfl_down(s,off);s2+=__shfl_down(s2,off);}
  __shared__ float ls[8];
  int wid=tid>>6,lane=tid&63;
  if(lane==0){ls[wid]=s;ls[4+wid]=s2;}
  __syncthreads();
  if(tid==0){
    float S=ls[0]+ls[1]+ls[2]+ls[3],S2=ls[4]+ls[5]+ls[6]+ls[7];
    float mu=S*(1.f/(Tz*DHz));
    float var=S2*(1.f/(Tz*DHz))-mu*mu;
    gmu[g]=mu; grs[g]=rsqrtf(fmaxf(var,0.f)+1e-5f);
  }
}

// ---------------- finish: coalesced transposed W_last ----------------
__global__ void __launch_bounds__(512,2) k_final(const float* __restrict__ hs,
    const float* __restrict__ gmu, const float* __restrict__ grs,
    const float* __restrict__ gng, const float* __restrict__ gnb,
    const float* __restrict__ sk, const float* __restrict__ xr,
    const float* __restrict__ WLt, const float* __restrict__ bl,
    const float* __restrict__ x, float* __restrict__ out){
  __shared__ float hm[4][D2z];      // 8KB
  __shared__ float4 red[8][4][64];  // 32KB
  int r0=blockIdx.x*4; int b=r0>>8; int tid=threadIdx.x;  // 512
  for(int idx=tid;idx<4*D2z;idx+=512){
    int tt=idx>>9,c=idx&511;
    size_t row=r0+tt;
    int g=(b<<2)+(c>>7);
    float v=hs[row*D2z+c];
    float hg=(v-gmu[g])*grs[g]*gng[c]+gnb[c]+sk[row*D2z+c];
    float xv=xr[row*D2z+c];
    hm[tt][c]=hg*(xv*sigmoidf_(xv));
  }
  __syncthreads();
  int ol=tid&63, ch=tid>>6;   // ch 0..7, k in [ch*64, ch*64+64)
  float4 a0={0,0,0,0},a1={0,0,0,0},a2={0,0,0,0},a3={0,0,0,0};
  const float4* wp=(const float4*)WLt + (size_t)(ch*64)*64 + ol;
  #pragma unroll 2
  for(int kq=0;kq<16;kq++){
    int k=ch*64+kq*4;
    float4 w0=wp[(kq*4+0)*64], w1=wp[(kq*4+1)*64], w2=wp[(kq*4+2)*64], w3=wp[(kq*4+3)*64];
    float4 x0=*(const float4*)&hm[0][k];
    float4 x1=*(const float4*)&hm[1][k];
    float4 x2=*(const float4*)&hm[2][k];
    float4 x3=*(const float4*)&hm[3][k];
    a0=fma4(fma4(fma4(fma4(a0,w0,x0.x),w1,x0.y),w2,x0.z),w3,x0.w);
    a1=fma4(fma4(fma4(fma4(a1,w0,x1.x),w1,x1.y),w2,x1.z),w3,x1.w);
    a2=fma4(fma4(fma4(fma4(a2,w0,x2.x),w1,x2.y),w2,x2.z),w3,x2.w);
    a3=fma4(fma4(fma4(fma4(a3,w0,x3.x),w1,x3.y),w2,x3.z),w3,x3.w);
  }
  red[ch][0][ol]=a0; red[ch][1][ol]=a1; red[ch][2][ol]=a2; red[ch][3][ol]=a3;
  __syncthreads();
  if(tid<256){
    int tt=tid>>6, oo=tid&63;
    float4 sv={0,0,0,0};
    #pragma unroll
    for(int c2=0;c2<8;c2++) sv=add4(sv,red[c2][tt][oo]);
    float4 bb=((const float4*)bl)[oo];
    float4 xv=((const float4*)(x+(size_t)(r0+tt)*Dz))[oo];
    sv.x+=bb.x+xv.x; sv.y+=bb.y+xv.y; sv.z+=bb.z+xv.z; sv.w+=bb.w+xv.w;
    ((float4*)(out+(size_t)(r0+tt)*Dz))[oo]=sv;
  }
}

extern "C" void kernel_launch(void* const* d_in, const int* in_sizes, int n_in,
                              void* d_out, int out_size, void* d_ws, size_t ws_size,
                              hipStream_t stream) {
  (void)in_sizes; (void)n_in; (void)out_size; (void)ws_size;
  const float* x      = (const float*)d_in[0];
  const float* ln_g   = (const float*)d_in[1];
  const float* ln_b   = (const float*)d_in[2];
  const float* W_left = (const float*)d_in[3];
  const float* b_left = (const float*)d_in[4];
  const float* W_right= (const float*)d_in[5];
  const float* b_right= (const float*)d_in[6];
  const float* Wi     = (const float*)d_in[7];
  const float* bi     = (const float*)d_in[8];
  const float* Wf     = (const float*)d_in[9];
  const float* bf     = (const float*)d_in[10];
  const float* Wo     = (const float*)d_in[11];
  const float* bo     = (const float*)d_in[12];
  const float* Wq     = (const float*)d_in[13];
  const float* Wk     = (const float*)d_in[14];
  const float* Wv     = (const float*)d_in[15];
  const float* conv_w = (const float*)d_in[16];
  const float* conv_b = (const float*)d_in[17];
  const float* skip_W = (const float*)d_in[18];
  const float* gn_g   = (const float*)d_in[19];
  const float* gn_b   = (const float*)d_in[20];
  const float* W_last = (const float*)d_in[21];
  const float* b_last = (const float*)d_in[22];
  float* out = (float*)d_out;

  float* ws = (float*)d_ws;
  float* Wot  = ws;                  // 262144 (old xn slot)
  float* xl   = ws + 262144;         // 524288
  float* xr   = ws + 786432;         // 524288
  float* xt   = ws + 1310720;        // 524288
  float* og   = ws + 1835008;        // 524288
  float* vv   = ws + 2359296;        // 524288
  float* qq   = ws + 2883584;        // 524288
  float* kk   = ws + 3407872;        // 524288
  float* sk   = ws + 3932160;        // 524288
  float* hs   = ws + 4456448;        // 524288
  float* ibp  = ws + 4980736;        // 2048
  float* fbp  = ws + 4982784;        // 2048
  float* gmu  = ws + 4984832;        // 16
  float* grs  = ws + 4984848;        // 16
  float* Gd   = ws + 4984864;        // 1024
  float* Mxd  = ws + 4985888;        // 1024
  float* SWt  = ws + 4986912;        // 262144
  float* WLt  = ws + 5249056;        // 131072
  float* Wqt  = ws + 5380128;        // 65536
  float* Wkt  = ws + 5445664;        // 65536
  float* Wvt  = ws + 5511200;        // 65536
  float* CWt  = ws + 5576736;        // 1048576

  k_tr    <<<464, 256, 0, stream>>>(Wo, skip_W, W_last, Wq, Wk, Wv, conv_w,
                                    Wot, SWt, WLt, Wqt, Wkt, Wvt, CWt);
  k_lnlr  <<<dim3(BT/8, 2), 512, 0, stream>>>(x, ln_g, ln_b, W_left, b_left, W_right, b_right,
                                              Wi, bi, Wf, bf, xl, xr, ibp, fbp);
  k_decay <<<Bz, 256, 0, stream>>>(ibp, fbp, Gd, Mxd);
  k_conv  <<<dim3(BT/8, 8), 256, 0, stream>>>(xl, CWt, conv_b, xt);
  k_wov   <<<dim3(BT/4, 2), 256, 0, stream>>>(xl, Wot, bo, Wvt, og, vv);
  k_qks   <<<dim3(BT/4, 2), 256, 0, stream>>>(xt, SWt, Wqt, Wkt, qq, kk, sk);
  k_attn  <<<dim3(Tz/TTa, Bz), 256, 0, stream>>>(qq, kk, vv, og, Gd, Mxd, hs);
  k_gnstat<<<Bz*Hz, 256, 0, stream>>>(hs, gmu, grs);
  k_final <<<BT/4, 512, 0, stream>>>(hs, gmu, grs, gn_g, gn_b, sk, xr, WLt, b_last, x, out);
}

// Round 7
// 186.226 us; speedup vs baseline: 2.0204x; 1.1142x over previous
//
#include <hip/hip_runtime.h>
#include <hip/hip_bf16.h>
#include <cstdint>

// Sizes
#define Bz 4
#define Tz 256
#define Dz 256
#define D2z 512
#define Hz 4
#define DHz 128
#define BT (Bz*Tz)          // 1024 rows

__device__ __forceinline__ float dot4(float4 a, float4 b){
  return a.x*b.x + a.y*b.y + a.z*b.z + a.w*b.w;
}
__device__ __forceinline__ float sigmoidf_(float z){ return 1.f/(1.f+__expf(-z)); }
__device__ __forceinline__ float4 fma4(float4 a, float4 w, float s){
  a.x += w.x*s; a.y += w.y*s; a.z += w.z*s; a.w += w.w*s; return a;
}
__device__ __forceinline__ float4 add4(float4 a, float4 b){
  a.x+=b.x; a.y+=b.y; a.z+=b.z; a.w+=b.w; return a;
}

// ---------------- one-shot weight transposes ----------------
__global__ void __launch_bounds__(256) k_tr(
    const float* __restrict__ Wo, const float* __restrict__ SW,
    const float* __restrict__ Wl, const float* __restrict__ Wq,
    const float* __restrict__ Wk, const float* __restrict__ Wv,
    const float* __restrict__ CW,
    float* __restrict__ Wot, float* __restrict__ SWt, float* __restrict__ WLt,
    float* __restrict__ Wqt, float* __restrict__ Wkt, float* __restrict__ Wvt,
    float* __restrict__ CWt){
  int bid = blockIdx.x, tid = threadIdx.x;
  if (bid < 208){
    __shared__ float ts[64][65];
    const float* src; float* dst; int O,K,to,tk;
    if (bid<64){ src=Wo; dst=Wot; O=512;K=512; to=bid>>3; tk=bid&7; }
    else if (bid<128){ int r=bid-64; src=SW; dst=SWt; O=512;K=512; to=r>>3; tk=r&7; }
    else if (bid<160){ int r=bid-128; src=Wl; dst=WLt; O=256;K=512; to=r>>3; tk=r&7; }
    else {
      int r=bid-160; int m=r>>4; int rr=r&15; int h=rr>>2; int s=rr&3;
      src=(m==0?Wq:m==1?Wk:Wv) + h*16384;
      dst=(m==0?Wqt:m==1?Wkt:Wvt) + h*16384;
      O=128; K=128; to=s>>1; tk=s&1;
    }
    int lk=tid&63, ro=tid>>6;
    #pragma unroll
    for(int p=0;p<16;p++) ts[p*4+ro][lk] = src[(size_t)(to*64+p*4+ro)*K + tk*64+lk];
    __syncthreads();
    #pragma unroll
    for(int p=0;p<16;p++) dst[(size_t)(tk*64+p*4+ro)*O + to*64+lk] = ts[lk][p*4+ro];
  } else {
    __shared__ float4 t4[32][33];
    int r = bid-208; int to=r>>4, tk=r&15;
    const float4* src4=(const float4*)CW; float4* dst4=(float4*)CWt;
    int li=tid&31, ro=tid>>5;
    #pragma unroll
    for(int p=0;p<4;p++) t4[p*8+ro][li] = src4[(size_t)(to*32+p*8+ro)*512 + tk*32+li];
    __syncthreads();
    #pragma unroll
    for(int p=0;p<4;p++) dst4[(size_t)(tk*32+p*8+ro)*512 + to*32+li] = t4[li][p*8+ro];
  }
}

// ---------------- fused LayerNorm + x_left/x_right GEMM + i/f partials ----------------
__global__ void __launch_bounds__(512,2) k_lnlr(
    const float* __restrict__ x, const float* __restrict__ lg,
    const float* __restrict__ lb, const float* __restrict__ WL,
    const float* __restrict__ bL, const float* __restrict__ WR,
    const float* __restrict__ bR,
    const float* __restrict__ Wi, const float* __restrict__ bi,
    const float* __restrict__ Wf, const float* __restrict__ bf,
    float* __restrict__ xl, float* __restrict__ xr,
    float* __restrict__ ibp, float* __restrict__ fbp){
  __shared__ float xs[8][Dz];
  __shared__ float rif[2][4][8];    // [i/f][wave 0-3][row]
  int r0 = blockIdx.x*8; int oh = blockIdx.y;
  int tid = threadIdx.x;            // 512
  ((float4*)&xs[0][0])[tid] = ((const float4*)(x + (size_t)r0*Dz))[tid];
  __syncthreads();
  int w = tid>>6, lane = tid&63;
  float a0 = xs[w][lane],     a1 = xs[w][lane+64];
  float a2 = xs[w][lane+128], a3 = xs[w][lane+192];
  float s  = a0+a1+a2+a3;
  float s2 = a0*a0+a1*a1+a2*a2+a3*a3;
  #pragma unroll
  for (int off=1; off<64; off<<=1){ s += __shfl_xor(s, off); s2 += __shfl_xor(s2, off); }
  float mu = s*(1.f/Dz);
  float rs = rsqrtf(s2*(1.f/Dz)-mu*mu+1e-5f);
  xs[w][lane]     = (a0-mu)*rs*lg[lane]    +lb[lane];
  xs[w][lane+64]  = (a1-mu)*rs*lg[lane+64] +lb[lane+64];
  xs[w][lane+128] = (a2-mu)*rs*lg[lane+128]+lb[lane+128];
  xs[w][lane+192] = (a3-mu)*rs*lg[lane+192]+lb[lane+192];
  __syncthreads();
  int which = tid>>8;               // 0 -> WL (+i/f), 1 -> WR
  int o = oh*256 + (tid&255);
  float acc[8]={0,0,0,0,0,0,0,0};
  const float* WM = which ? WR : WL;
  const float4* wm4 = (const float4*)(WM + (size_t)o*Dz);
  #pragma unroll 2
  for (int k4=0;k4<Dz/4;k4++){
    float4 wv=wm4[k4];
    #pragma unroll
    for(int tt=0;tt<8;tt++) acc[tt] += dot4(wv, ((const float4*)xs[tt])[k4]);
  }
  if (which==0){
    float blv=bL[o], wi_o=Wi[o], wf_o=Wf[o];
    float pi[8], pf[8];
    #pragma unroll
    for(int tt=0;tt<8;tt++){
      float xlv = acc[tt]+blv;
      xl[(size_t)(r0+tt)*D2z+o]=xlv;
      pi[tt]=xlv*wi_o; pf[tt]=xlv*wf_o;
    }
    #pragma unroll
    for(int off=1;off<64;off<<=1){
      #pragma unroll
      for(int tt=0;tt<8;tt++){ pi[tt]+=__shfl_xor(pi[tt],off); pf[tt]+=__shfl_xor(pf[tt],off); }
    }
    if(lane==0){
      #pragma unroll
      for(int tt=0;tt<8;tt++){ rif[0][w][tt]=pi[tt]; rif[1][w][tt]=pf[tt]; }
    }
  } else {
    float brv=bR[o];
    #pragma unroll
    for(int tt=0;tt<8;tt++) xr[(size_t)(r0+tt)*D2z+o]=acc[tt]+brv;
  }
  __syncthreads();
  if(tid<16){
    int r=tid&7, which2=tid>>3;
    float sv=0.f;
    #pragma unroll
    for(int ww=0;ww<4;ww++) sv+=rif[which2][ww][r];
    float bias = (oh==0) ? (which2==0 ? bi[0] : bf[0]) : 0.f;
    (which2==0 ? ibp : fbp)[oh*BT + r0 + r] = sv + bias;
  }
}

// ---------------- fused mid: conv(t-tile 16) + wov + decay, blockIdx-dispatched ----------------
// bid [0,512):  conv  — t-tile 16, 8 o-groups, in-block ic-chunk reduce. LDS 56.3 KB.
// bid [512,1024): wov — 4 rows, 2 o-halves (o-gate GEMM + block-diag v).
// bid [1024,1028): decay prefix-scan.
__global__ void __launch_bounds__(256,2) k_mid(
    const float* __restrict__ xl, const float* __restrict__ CWt,
    const float* __restrict__ cb, float* __restrict__ xt,
    const float* __restrict__ Wot, const float* __restrict__ bo,
    const float* __restrict__ Wvt, float* __restrict__ og, float* __restrict__ vv,
    const float* __restrict__ ibp, const float* __restrict__ fbp,
    float* __restrict__ G, float* __restrict__ Mx){
  __shared__ __align__(16) float smem[14080];   // 56320 B
  int bid = blockIdx.x, tid = threadIdx.x;      // 256 thr
  if (bid < 512){
    // ---------------- conv ----------------
    float (*xs)[D2z] = (float(*)[D2z])smem;                    // [19][512]
    float (*red)[64][17] = (float(*)[64][17])(smem + 19*D2z);  // [4][64][17]
    int tile = bid&63, o0 = (bid>>6)*64;
    int b = tile>>4; int t0 = (tile&15)*16;
    for(int idx=tid; idx<19*(D2z/4); idx+=256){
      int j = idx>>7, k4 = idx&127;
      int t = t0-3+j;
      float4 v = (t>=0) ? ((const float4*)(xl + (size_t)((b<<8)+t)*D2z))[k4]
                        : make_float4(0.f,0.f,0.f,0.f);
      ((float4*)xs[j])[k4]=v;
    }
    __syncthreads();
    int ol = tid&63, ch = tid>>6;
    int o = o0 + ol, ic0 = ch*128;
    float acc[16];
    #pragma unroll
    for(int tt=0;tt<16;tt++) acc[tt]=0.f;
    const float4* w4 = (const float4*)CWt + o;   // quad index [i*512 + o]
    for(int i=0;i<128;i+=4){
      int ig = ic0+i;
      float4 w0=w4[(size_t)(ig+0)*512], w1=w4[(size_t)(ig+1)*512];
      float4 w2=w4[(size_t)(ig+2)*512], w3=w4[(size_t)(ig+3)*512];
      float4 xr4[19];
      #pragma unroll
      for(int j=0;j<19;j++) xr4[j]=*(const float4*)&xs[j][ig];
      #pragma unroll
      for(int tt=0;tt<16;tt++){
        acc[tt] += w0.x*xr4[tt].x + w0.y*xr4[tt+1].x + w0.z*xr4[tt+2].x + w0.w*xr4[tt+3].x
                 + w1.x*xr4[tt].y + w1.y*xr4[tt+1].y + w1.z*xr4[tt+2].y + w1.w*xr4[tt+3].y
                 + w2.x*xr4[tt].z + w2.y*xr4[tt+1].z + w2.z*xr4[tt+2].z + w2.w*xr4[tt+3].z
                 + w3.x*xr4[tt].w + w3.y*xr4[tt+1].w + w3.z*xr4[tt+2].w + w3.w*xr4[tt+3].w;
      }
    }
    #pragma unroll
    for(int tt=0;tt<16;tt++) red[ch][ol][tt]=acc[tt];
    __syncthreads();
    for(int idx=tid; idx<1024; idx+=256){
      int oo = idx&63, t = idx>>6;
      float y = red[0][oo][t]+red[1][oo][t]+red[2][oo][t]+red[3][oo][t] + cb[o0+oo];
      xt[(size_t)((b<<8)+t0+t)*D2z + o0+oo] = y*sigmoidf_(y);
    }
  } else if (bid < 1024){
    // ---------------- wov ----------------
    float (*xs)[D2z] = (float(*)[D2z])smem;                          // [4][512] 8KB
    float4 (*ored)[4][64] = (float4(*)[4][64])(smem + 4*D2z);        // 16KB
    float4 (*vred)[4][64] = (float4(*)[4][64])(smem + 4*D2z + 4096); // 16KB
    int wbid = bid-512;
    int r0=(wbid&255)*4; int oh=wbid>>8;
    for(int idx=tid;idx<512;idx+=256)
      ((float4*)&xs[0][0])[idx]=((const float4*)(xl+(size_t)r0*D2z))[idx];
    __syncthreads();
    int ol=tid&63, ch=tid>>6;
    float4 a0={0,0,0,0},a1={0,0,0,0},a2={0,0,0,0},a3={0,0,0,0};
    const float4* wp=(const float4*)Wot + (size_t)ch*16384 + (oh*64+ol);
    #pragma unroll 2
    for(int kq=0;kq<32;kq++){
      int k=ch*128+kq*4;
      float4 w0=wp[(kq*4+0)*128], w1=wp[(kq*4+1)*128], w2=wp[(kq*4+2)*128], w3=wp[(kq*4+3)*128];
      float4 x0=*(const float4*)&xs[0][k];
      float4 x1=*(const float4*)&xs[1][k];
      float4 x2=*(const float4*)&xs[2][k];
      float4 x3=*(const float4*)&xs[3][k];
      a0=fma4(fma4(fma4(fma4(a0,w0,x0.x),w1,x0.y),w2,x0.z),w3,x0.w);
      a1=fma4(fma4(fma4(fma4(a1,w0,x1.x),w1,x1.y),w2,x1.z),w3,x1.w);
      a2=fma4(fma4(fma4(fma4(a2,w0,x2.x),w1,x2.y),w2,x2.z),w3,x2.w);
      a3=fma4(fma4(fma4(fma4(a3,w0,x3.x),w1,x3.y),w2,x3.z),w3,x3.w);
    }
    ored[ch][0][ol]=a0; ored[ch][1][ol]=a1; ored[ch][2][ol]=a2; ored[ch][3][ol]=a3;
    {
      int h = oh*2 + (ol>>5), odq = ol&31;
      float4 v0={0,0,0,0},v1={0,0,0,0},v2={0,0,0,0},v3={0,0,0,0};
      const float4* wv=(const float4*)Wvt + (size_t)h*4096 + (size_t)(ch*32)*32 + odq;
      int xoff = h*128 + ch*32;
      #pragma unroll 2
      for(int iq=0;iq<8;iq++){
        float4 w0=wv[(iq*4+0)*32], w1=wv[(iq*4+1)*32], w2=wv[(iq*4+2)*32], w3=wv[(iq*4+3)*32];
        float4 x0=*(const float4*)&xs[0][xoff+iq*4];
        float4 x1=*(const float4*)&xs[1][xoff+iq*4];
        float4 x2=*(const float4*)&xs[2][xoff+iq*4];
        float4 x3=*(const float4*)&xs[3][xoff+iq*4];
        v0=fma4(fma4(fma4(fma4(v0,w0,x0.x),w1,x0.y),w2,x0.z),w3,x0.w);
        v1=fma4(fma4(fma4(fma4(v1,w0,x1.x),w1,x1.y),w2,x1.z),w3,x1.w);
        v2=fma4(fma4(fma4(fma4(v2,w0,x2.x),w1,x2.y),w2,x2.z),w3,x2.w);
        v3=fma4(fma4(fma4(fma4(v3,w0,x3.x),w1,x3.y),w2,x3.z),w3,x3.w);
      }
      vred[ch][0][ol]=v0; vred[ch][1][ol]=v1; vred[ch][2][ol]=v2; vred[ch][3][ol]=v3;
    }
    __syncthreads();
    int tt=tid>>6, oo=tid&63;
    float4 s=add4(add4(ored[0][tt][oo],ored[1][tt][oo]),add4(ored[2][tt][oo],ored[3][tt][oo]));
    float4 bb=((const float4*)bo)[oh*64+oo];
    s.x=sigmoidf_(s.x+bb.x); s.y=sigmoidf_(s.y+bb.y);
    s.z=sigmoidf_(s.z+bb.z); s.w=sigmoidf_(s.w+bb.w);
    float4 vs=add4(add4(vred[0][tt][oo],vred[1][tt][oo]),add4(vred[2][tt][oo],vred[3][tt][oo]));
    size_t row=r0+tt;
    ((float4*)(og+row*D2z))[oh*64+oo]=s;
    ((float4*)(vv+row*D2z))[oh*64+oo]=vs;
  } else {
    // ---------------- decay ----------------
    float* buf = smem;
    int b = bid-1024, t = tid;
    float f = fbp[b*Tz + t] + fbp[BT + b*Tz + t];
    float ibv = ibp[b*Tz + t] + ibp[BT + b*Tz + t];
    buf[t] = f; __syncthreads();
    float v = f;
    for (int off=1; off<Tz; off<<=1){
      float add = (t >= off) ? buf[t-off] : 0.f;
      __syncthreads();
      v += add; buf[t] = v;
      __syncthreads();
    }
    float F = v;
    float g = ibv - F;
    G[b*Tz+t] = g;
    buf[t] = g; __syncthreads();
    v = g;
    for (int off=1; off<Tz; off<<=1){
      float other = (t >= off) ? buf[t-off] : -3.4e38f;
      __syncthreads();
      v = fmaxf(v, other); buf[t] = v;
      __syncthreads();
    }
    Mx[b*Tz+t] = fmaxf(v, 0.f);
  }
}

// ---------------- q,k (block-diag) + skip GEMM, coalesced transposed weights ----------------
__global__ void __launch_bounds__(256,2) k_qks(const float* __restrict__ xt,
    const float* __restrict__ SWt, const float* __restrict__ Wqt,
    const float* __restrict__ Wkt,
    float* __restrict__ qq, float* __restrict__ kk, float* __restrict__ sk){
  __shared__ float xs[4][D2z];          // 8KB
  __shared__ float4 sred[4][4][64];     // 16KB
  __shared__ float4 qred[4][4][64];     // 16KB
  __shared__ float4 kred[4][4][64];     // 16KB
  int r0=blockIdx.x*4; int oh=blockIdx.y; int tid=threadIdx.x;
  for(int idx=tid;idx<512;idx+=256)
    ((float4*)&xs[0][0])[idx]=((const float4*)(xt+(size_t)r0*D2z))[idx];
  __syncthreads();
  int ol=tid&63, ch=tid>>6;
  float4 s0={0,0,0,0},s1={0,0,0,0},s2={0,0,0,0},s3={0,0,0,0};
  const float4* wp=(const float4*)SWt + (size_t)ch*16384 + (oh*64+ol);
  #pragma unroll 2
  for(int kq=0;kq<32;kq++){
    int k=ch*128+kq*4;
    float4 w0=wp[(kq*4+0)*128], w1=wp[(kq*4+1)*128], w2=wp[(kq*4+2)*128], w3=wp[(kq*4+3)*128];
    float4 x0=*(const float4*)&xs[0][k];
    float4 x1=*(const float4*)&xs[1][k];
    float4 x2=*(const float4*)&xs[2][k];
    float4 x3=*(const float4*)&xs[3][k];
    s0=fma4(fma4(fma4(fma4(s0,w0,x0.x),w1,x0.y),w2,x0.z),w3,x0.w);
    s1=fma4(fma4(fma4(fma4(s1,w0,x1.x),w1,x1.y),w2,x1.z),w3,x1.w);
    s2=fma4(fma4(fma4(fma4(s2,w0,x2.x),w1,x2.y),w2,x2.z),w3,x2.w);
    s3=fma4(fma4(fma4(fma4(s3,w0,x3.x),w1,x3.y),w2,x3.z),w3,x3.w);
  }
  sred[ch][0][ol]=s0; sred[ch][1][ol]=s1; sred[ch][2][ol]=s2; sred[ch][3][ol]=s3;
  {
    int h = oh*2 + (ol>>5), odq = ol&31;
    float4 q0={0,0,0,0},q1={0,0,0,0},q2={0,0,0,0},q3={0,0,0,0};
    float4 c0={0,0,0,0},c1={0,0,0,0},c2={0,0,0,0},c3={0,0,0,0};
    const float4* wq=(const float4*)Wqt + (size_t)h*4096 + (size_t)(ch*32)*32 + odq;
    const float4* wk=(const float4*)Wkt + (size_t)h*4096 + (size_t)(ch*32)*32 + odq;
    int xoff = h*128 + ch*32;
    #pragma unroll 2
    for(int iq=0;iq<8;iq++){
      float4 qa0=wq[(iq*4+0)*32], qa1=wq[(iq*4+1)*32], qa2=wq[(iq*4+2)*32], qa3=wq[(iq*4+3)*32];
      float4 ka0=wk[(iq*4+0)*32], ka1=wk[(iq*4+1)*32], ka2=wk[(iq*4+2)*32], ka3=wk[(iq*4+3)*32];
      float4 x0=*(const float4*)&xs[0][xoff+iq*4];
      float4 x1=*(const float4*)&xs[1][xoff+iq*4];
      float4 x2=*(const float4*)&xs[2][xoff+iq*4];
      float4 x3=*(const float4*)&xs[3][xoff+iq*4];
      q0=fma4(fma4(fma4(fma4(q0,qa0,x0.x),qa1,x0.y),qa2,x0.z),qa3,x0.w);
      q1=fma4(fma4(fma4(fma4(q1,qa0,x1.x),qa1,x1.y),qa2,x1.z),qa3,x1.w);
      q2=fma4(fma4(fma4(fma4(q2,qa0,x2.x),qa1,x2.y),qa2,x2.z),qa3,x2.w);
      q3=fma4(fma4(fma4(fma4(q3,qa0,x3.x),qa1,x3.y),qa2,x3.z),qa3,x3.w);
      c0=fma4(fma4(fma4(fma4(c0,ka0,x0.x),ka1,x0.y),ka2,x0.z),ka3,x0.w);
      c1=fma4(fma4(fma4(fma4(c1,ka0,x1.x),ka1,x1.y),ka2,x1.z),ka3,x1.w);
      c2=fma4(fma4(fma4(fma4(c2,ka0,x2.x),ka1,x2.y),ka2,x2.z),ka3,x2.w);
      c3=fma4(fma4(fma4(fma4(c3,ka0,x3.x),ka1,x3.y),ka2,x3.z),ka3,x3.w);
    }
    qred[ch][0][ol]=q0; qred[ch][1][ol]=q1; qred[ch][2][ol]=q2; qred[ch][3][ol]=q3;
    kred[ch][0][ol]=c0; kred[ch][1][ol]=c1; kred[ch][2][ol]=c2; kred[ch][3][ol]=c3;
  }
  __syncthreads();
  int tt=tid>>6, oo=tid&63;
  float4 sv=add4(add4(sred[0][tt][oo],sred[1][tt][oo]),add4(sred[2][tt][oo],sred[3][tt][oo]));
  float4 qv=add4(add4(qred[0][tt][oo],qred[1][tt][oo]),add4(qred[2][tt][oo],qred[3][tt][oo]));
  float4 kv=add4(add4(kred[0][tt][oo],kred[1][tt][oo]),add4(kred[2][tt][oo],kred[3][tt][oo]));
  kv.x*=0.0625f; kv.y*=0.0625f; kv.z*=0.0625f; kv.w*=0.0625f;   // SCALE = D^-0.5
  size_t row=r0+tt;
  ((float4*)(sk+row*D2z))[oh*64+oo]=sv;
  ((float4*)(qq+row*D2z))[oh*64+oo]=qv;
  ((float4*)(kk+row*D2z))[oh*64+oo]=kv;
}

// ---------------- scan as causal decayed attention: TTa=4, grid (64, B) ----------------
#define TTa 4
__global__ void __launch_bounds__(256) k_attn(
    const float* __restrict__ qq, const float* __restrict__ kk,
    const float* __restrict__ vv, const float* __restrict__ og,
    const float* __restrict__ G, const float* __restrict__ Mx,
    float* __restrict__ hs){
  int b  = blockIdx.y;
  int t0 = blockIdx.x * TTa;
  int tid = threadIdx.x;            // 256
  __shared__ float Qs[TTa][D2z];
  __shared__ float Ps[TTa][Tz];
  __shared__ float Gs[Tz];
  __shared__ float inv_d[TTa];
  __shared__ float mxs[TTa];

  const float* qb = qq + ((size_t)b*Tz + t0)*D2z;
  for (int idx=tid; idx<TTa*D2z/4; idx+=256)
    ((float4*)&Qs[0][0])[idx] = ((const float4*)qb)[idx];
  Gs[tid] = G[b*Tz + tid];
  if (tid < TTa) mxs[tid] = Mx[b*Tz + t0 + tid];
  __syncthreads();

  int s = tid;
  int smax = t0 + TTa - 1;
  {
    float acc[TTa] = {0,0,0,0};
    if (s <= smax){
      const float4* kp = (const float4*)(kk + ((size_t)b*Tz + s)*D2z);
      for (int k4=0; k4<D2z/4; k4++){
        float4 kv = kp[k4];
        #pragma unroll
        for (int tt=0; tt<TTa; tt++){
          float4 qv = ((const float4*)Qs[tt])[k4];
          acc[tt] += dot4(kv,qv);
        }
      }
    }
    float g = Gs[s];
    #pragma unroll
    for (int tt=0; tt<TTa; tt++){
      int t = t0 + tt;
      Ps[tt][s] = (s <= t) ? acc[tt] * __expf(g - mxs[tt]) : 0.f;
    }
  }
  __syncthreads();
  {
    int wv = tid >> 6, lane = tid & 63;
    int tt = wv;
    float ssum = Ps[tt][lane] + Ps[tt][lane+64] + Ps[tt][lane+128] + Ps[tt][lane+192];
    #pragma unroll
    for (int off=1; off<64; off<<=1) ssum += __shfl_xor(ssum, off);
    if (lane==0) inv_d[tt] = 1.f / (fmaxf(fabsf(ssum), 1.f) + 1e-8f);
  }
  __syncthreads();
  {
    int c0 = tid, c1 = tid + 256;
    float a0[TTa]={0,0,0,0}, a1[TTa]={0,0,0,0};
    const float* vb = vv + (size_t)b*Tz*D2z;
    for (int s2=0; s2<=smax; s2+=4){
      float4 pr[TTa];
      #pragma unroll
      for (int tt=0; tt<TTa; tt++) pr[tt] = *(const float4*)&Ps[tt][s2];
      #pragma unroll
      for (int j=0; j<4; j++){
        int sj = s2 + j;
        float v0 = vb[(size_t)sj*D2z + c0];
        float v1 = vb[(size_t)sj*D2z + c1];
        #pragma unroll
        for (int tt=0; tt<TTa; tt++){
          float p = ((const float*)&pr[tt])[j];
          a0[tt] += p*v0; a1[tt] += p*v1;
        }
      }
    }
    #pragma unroll
    for (int tt=0; tt<TTa; tt++){
      size_t row = (size_t)b*Tz + t0 + tt;
      float id = inv_d[tt];
      hs[row*D2z + c0] = og[row*D2z + c0] * a0[tt] * id;
      hs[row*D2z + c1] = og[row*D2z + c1] * a1[tt] * id;
    }
  }
}

// ---------------- GroupNorm stats per (b,h) ----------------
__global__ void k_gnstat(const float* __restrict__ hs,float* __restrict__ gmu,
                         float* __restrict__ grs){
  int g=blockIdx.x; int b=g>>2,h=g&3; int tid=threadIdx.x;
  float s=0.f,s2=0.f;
  const float* base=hs+(size_t)b*Tz*D2z+h*DHz;
  for(int idx=tid;idx<Tz*DHz;idx+=256){
    int t=idx>>7,c=idx&127;
    float v=base[(size_t)t*D2z+c];
    s+=v;s2+=v*v;
  }
  #pragma unroll
  for(int off=32;off;off>>=1){s+=__shfl_down(s,off);s2+=__shfl_down(s2,off);}
  __shared__ float ls[8];
  int wid=tid>>6,lane=tid&63;
  if(lane==0){ls[wid]=s;ls[4+wid]=s2;}
  __syncthreads();
  if(tid==0){
    float S=ls[0]+ls[1]+ls[2]+ls[3],S2=ls[4]+ls[5]+ls[6]+ls[7];
    float mu=S*(1.f/(Tz*DHz));
    float var=S2*(1.f/(Tz*DHz))-mu*mu;
    gmu[g]=mu; grs[g]=rsqrtf(fmaxf(var,0.f)+1e-5f);
  }
}

// ---------------- finish: coalesced transposed W_last ----------------
__global__ void __launch_bounds__(512,2) k_final(const float* __restrict__ hs,
    const float* __restrict__ gmu, const float* __restrict__ grs,
    const float* __restrict__ gng, const float* __restrict__ gnb,
    const float* __restrict__ sk, const float* __restrict__ xr,
    const float* __restrict__ WLt, const float* __restrict__ bl,
    const float* __restrict__ x, float* __restrict__ out){
  __shared__ float hm[4][D2z];      // 8KB
  __shared__ float4 red[8][4][64];  // 32KB
  int r0=blockIdx.x*4; int b=r0>>8; int tid=threadIdx.x;  // 512
  for(int idx=tid;idx<4*D2z;idx+=512){
    int tt=idx>>9,c=idx&511;
    size_t row=r0+tt;
    int g=(b<<2)+(c>>7);
    float v=hs[row*D2z+c];
    float hg=(v-gmu[g])*grs[g]*gng[c]+gnb[c]+sk[row*D2z+c];
    float xv=xr[row*D2z+c];
    hm[tt][c]=hg*(xv*sigmoidf_(xv));
  }
  __syncthreads();
  int ol=tid&63, ch=tid>>6;   // ch 0..7, k in [ch*64, ch*64+64)
  float4 a0={0,0,0,0},a1={0,0,0,0},a2={0,0,0,0},a3={0,0,0,0};
  const float4* wp=(const float4*)WLt + (size_t)(ch*64)*64 + ol;
  #pragma unroll 2
  for(int kq=0;kq<16;kq++){
    int k=ch*64+kq*4;
    float4 w0=wp[(kq*4+0)*64], w1=wp[(kq*4+1)*64], w2=wp[(kq*4+2)*64], w3=wp[(kq*4+3)*64];
    float4 x0=*(const float4*)&hm[0][k];
    float4 x1=*(const float4*)&hm[1][k];
    float4 x2=*(const float4*)&hm[2][k];
    float4 x3=*(const float4*)&hm[3][k];
    a0=fma4(fma4(fma4(fma4(a0,w0,x0.x),w1,x0.y),w2,x0.z),w3,x0.w);
    a1=fma4(fma4(fma4(fma4(a1,w0,x1.x),w1,x1.y),w2,x1.z),w3,x1.w);
    a2=fma4(fma4(fma4(fma4(a2,w0,x2.x),w1,x2.y),w2,x2.z),w3,x2.w);
    a3=fma4(fma4(fma4(fma4(a3,w0,x3.x),w1,x3.y),w2,x3.z),w3,x3.w);
  }
  red[ch][0][ol]=a0; red[ch][1][ol]=a1; red[ch][2][ol]=a2; red[ch][3][ol]=a3;
  __syncthreads();
  if(tid<256){
    int tt=tid>>6, oo=tid&63;
    float4 sv={0,0,0,0};
    #pragma unroll
    for(int c2=0;c2<8;c2++) sv=add4(sv,red[c2][tt][oo]);
    float4 bb=((const float4*)bl)[oo];
    float4 xv=((const float4*)(x+(size_t)(r0+tt)*Dz))[oo];
    sv.x+=bb.x+xv.x; sv.y+=bb.y+xv.y; sv.z+=bb.z+xv.z; sv.w+=bb.w+xv.w;
    ((float4*)(out+(size_t)(r0+tt)*Dz))[oo]=sv;
  }
}

extern "C" void kernel_launch(void* const* d_in, const int* in_sizes, int n_in,
                              void* d_out, int out_size, void* d_ws, size_t ws_size,
                              hipStream_t stream) {
  (void)in_sizes; (void)n_in; (void)out_size; (void)ws_size;
  const float* x      = (const float*)d_in[0];
  const float* ln_g   = (const float*)d_in[1];
  const float* ln_b   = (const float*)d_in[2];
  const float* W_left = (const float*)d_in[3];
  const float* b_left = (const float*)d_in[4];
  const float* W_right= (const float*)d_in[5];
  const float* b_right= (const float*)d_in[6];
  const float* Wi     = (const float*)d_in[7];
  const float* bi     = (const float*)d_in[8];
  const float* Wf     = (const float*)d_in[9];
  const float* bf     = (const float*)d_in[10];
  const float* Wo     = (const float*)d_in[11];
  const float* bo     = (const float*)d_in[12];
  const float* Wq     = (const float*)d_in[13];
  const float* Wk     = (const float*)d_in[14];
  const float* Wv     = (const float*)d_in[15];
  const float* conv_w = (const float*)d_in[16];
  const float* conv_b = (const float*)d_in[17];
  const float* skip_W = (const float*)d_in[18];
  const float* gn_g   = (const float*)d_in[19];
  const float* gn_b   = (const float*)d_in[20];
  const float* W_last = (const float*)d_in[21];
  const float* b_last = (const float*)d_in[22];
  float* out = (float*)d_out;

  float* ws = (float*)d_ws;
  float* Wot  = ws;                  // 262144
  float* xl   = ws + 262144;         // 524288
  float* xr   = ws + 786432;         // 524288
  float* xt   = ws + 1310720;        // 524288
  float* og   = ws + 1835008;        // 524288
  float* vv   = ws + 2359296;        // 524288
  float* qq   = ws + 2883584;        // 524288
  float* kk   = ws + 3407872;        // 524288
  float* sk   = ws + 3932160;        // 524288
  float* hs   = ws + 4456448;        // 524288
  float* ibp  = ws + 4980736;        // 2048
  float* fbp  = ws + 4982784;        // 2048
  float* gmu  = ws + 4984832;        // 16
  float* grs  = ws + 4984848;        // 16
  float* Gd   = ws + 4984864;        // 1024
  float* Mxd  = ws + 4985888;        // 1024
  float* SWt  = ws + 4986912;        // 262144
  float* WLt  = ws + 5249056;        // 131072
  float* Wqt  = ws + 5380128;        // 65536
  float* Wkt  = ws + 5445664;        // 65536
  float* Wvt  = ws + 5511200;        // 65536
  float* CWt  = ws + 5576736;        // 1048576

  k_tr    <<<464, 256, 0, stream>>>(Wo, skip_W, W_last, Wq, Wk, Wv, conv_w,
                                    Wot, SWt, WLt, Wqt, Wkt, Wvt, CWt);
  k_lnlr  <<<dim3(BT/8, 2), 512, 0, stream>>>(x, ln_g, ln_b, W_left, b_left, W_right, b_right,
                                              Wi, bi, Wf, bf, xl, xr, ibp, fbp);
  k_mid   <<<1028, 256, 0, stream>>>(xl, CWt, conv_b, xt, Wot, bo, Wvt, og, vv,
                                     ibp, fbp, Gd, Mxd);
  k_qks   <<<dim3(BT/4, 2), 256, 0, stream>>>(xt, SWt, Wqt, Wkt, qq, kk, sk);
  k_attn  <<<dim3(Tz/TTa, Bz), 256, 0, stream>>>(qq, kk, vv, og, Gd, Mxd, hs);
  k_gnstat<<<Bz*Hz, 256, 0, stream>>>(hs, gmu, grs);
  k_final <<<BT/4, 512, 0, stream>>>(hs, gmu, grs, gn_g, gn_b, sk, xr, WLt, b_last, x, out);
}